// Round 1
// baseline (5141.194 us; speedup 1.0000x reference)
//
#include <hip/hip_runtime.h>
#include <math.h>

// HELPv3: 8-layer bipartite GAT (human<->object) + pooling + 2 softmax heads.
// fp32 baseline. Structure:
//   - vd = Wdst@adst / vs = Wsrc@asrc precomputed -> a_d/a_s are GEMVs (kills half the GEMMs)
//   - dst-sorted CSR built once per launch -> atomic-free per-dst segment softmax (1 wave/dst)
//   - 16 GEMMs [50000,256]x[256,256] fp32 LDS-tiled 64x64
// ws usage ~267MB.

#define NNODE 50000
#define EDG   500000
#define DIM   256
#define LAY   8
#define BB    512
#define CC    117
#define EMBD  544

static __device__ __forceinline__ float lrelu(float x){ return x >= 0.f ? x : 0.2f*x; }

// v[k] = sum_j W[k*256+j]*a[j] for 32 (l,rel,which) combos; one wave per output k
__global__ void vcompute_k(const float* __restrict__ Wsho, const float* __restrict__ Wdho,
                           const float* __restrict__ asho, const float* __restrict__ adho,
                           const float* __restrict__ Wsoh, const float* __restrict__ Wdoh,
                           const float* __restrict__ asoh, const float* __restrict__ adoh,
                           float* __restrict__ vbuf){
  int gid = blockIdx.x*blockDim.x + threadIdx.x;
  int wv = gid >> 6, lane = gid & 63;
  if (wv >= 32*DIM) return;
  int p = wv >> 8, k = wv & 255;
  int which = p & 1, rel = (p>>1)&1, l = p>>2;
  const float* W; const float* a;
  if (rel==0){ W = which? Wdho : Wsho; a = which? adho : asho; }
  else       { W = which? Wdoh : Wsoh; a = which? adoh : asoh; }
  W += (size_t)l*DIM*DIM; a += (size_t)l*DIM;
  const float4* w4 = (const float4*)(W + (size_t)k*DIM);
  const float4* a4 = (const float4*)a;
  float4 wv4 = w4[lane], av4 = a4[lane];
  float s = wv4.x*av4.x + wv4.y*av4.y + wv4.z*av4.z + wv4.w*av4.w;
  for (int off=32; off; off>>=1) s += __shfl_xor(s, off);
  if (lane==0) vbuf[(size_t)p*DIM + k] = s;
}

// per (l,rel): w0 = Wedge[l][0,:]·aedge[l], w1 = Wedge[l][1,:]·aedge[l]
__global__ void wecompute_k(const float* __restrict__ Weho, const float* __restrict__ aeho,
                            const float* __restrict__ Weoh, const float* __restrict__ aeoh,
                            float* __restrict__ webuf){
  int blk = blockIdx.x;            // l*2 + rel
  int rel = blk & 1, l = blk >> 1;
  const float* We = rel? Weoh : Weho;
  const float* ae = rel? aeoh : aeho;
  int lane = threadIdx.x;          // 64
  const float4* w0 = (const float4*)(We + (size_t)l*2*DIM);
  const float4* w1 = (const float4*)(We + (size_t)l*2*DIM + DIM);
  const float4* a4 = (const float4*)(ae + (size_t)l*DIM);
  float4 av = a4[lane], x0 = w0[lane], x1 = w1[lane];
  float s0 = x0.x*av.x + x0.y*av.y + x0.z*av.z + x0.w*av.w;
  float s1 = x1.x*av.x + x1.y*av.y + x1.z*av.z + x1.w*av.w;
  for (int off=32; off; off>>=1){ s0 += __shfl_xor(s0, off); s1 += __shfl_xor(s1, off); }
  if (lane==0){ webuf[blk*2] = s0; webuf[blk*2+1] = s1; }
}

__global__ void hist_k(const int* __restrict__ ei, int* __restrict__ cnt){
  int e = blockIdx.x*blockDim.x + threadIdx.x;
  if (e < EDG) atomicAdd(&cnt[ei[EDG + e]], 1);
}

__global__ void scan_k(const int* __restrict__ cnt, int* __restrict__ rowptr, int N){
  __shared__ int ps[1024];
  int t = threadIdx.x;
  int CH = (N + 1023) >> 10;
  int base = t*CH;
  int s = 0;
  for (int i=0;i<CH;i++){ int idx=base+i; if (idx<N) s += cnt[idx]; }
  ps[t] = s; __syncthreads();
  for (int off=1; off<1024; off<<=1){
    int v = 0;
    if (t >= off) v = ps[t-off];
    __syncthreads();
    ps[t] += v;
    __syncthreads();
  }
  int run = ps[t] - s;
  for (int i=0;i<CH;i++){ int idx=base+i; if (idx<N){ rowptr[idx] = run; run += cnt[idx]; } }
  if (t == 1023) rowptr[N] = ps[1023];
}

__global__ void scatter_k(const int* __restrict__ ei, const int* __restrict__ rowptr,
                          int* __restrict__ cursor, int* __restrict__ srcs, int* __restrict__ eids){
  int e = blockIdx.x*blockDim.x + threadIdx.x;
  if (e >= EDG) return;
  int d = ei[EDG + e];
  int pos = rowptr[d] + atomicAdd(&cursor[d], 1);
  srcs[pos] = ei[e];
  eids[pos] = e;
}

// H[N,256] = X[N,256] @ W[256,256]; 64x64 tile, 256 thr, 4x4 microtile
__global__ void gemm_k(const float* __restrict__ X, const float* __restrict__ W,
                       float* __restrict__ H, int N){
  __shared__ float As[16][68];
  __shared__ float Bs[16][64];
  int tid = threadIdx.x;
  int bx = blockIdx.x & 3, by = blockIdx.x >> 2;
  int row0 = by*64, col0 = bx*64;
  int tx = tid & 15, ty = tid >> 4;
  float acc[4][4] = {};
  int lr = tid >> 2;          // 0..63 tile row (X load)
  int lk = (tid & 3) * 4;     // k offset (X load)
  int wk = tid >> 6;          // 0..3 (W load)
  int wc = tid & 63;
  for (int k0 = 0; k0 < DIM; k0 += 16){
    float4 xv = make_float4(0.f,0.f,0.f,0.f);
    int xr = row0 + lr;
    if (xr < N) xv = *(const float4*)(X + (size_t)xr*DIM + k0 + lk);
    As[lk+0][lr] = xv.x; As[lk+1][lr] = xv.y; As[lk+2][lr] = xv.z; As[lk+3][lr] = xv.w;
    #pragma unroll
    for (int i=0;i<4;i++)
      Bs[wk + i*4][wc] = W[(size_t)(k0 + wk + i*4)*DIM + col0 + wc];
    __syncthreads();
    #pragma unroll
    for (int k=0;k<16;k++){
      float4 av = *(const float4*)&As[k][ty*4];
      float4 bv = *(const float4*)&Bs[k][tx*4];
      float ar[4] = {av.x, av.y, av.z, av.w};
      float br[4] = {bv.x, bv.y, bv.z, bv.w};
      #pragma unroll
      for (int i=0;i<4;i++)
        #pragma unroll
        for (int j=0;j<4;j++)
          acc[i][j] += ar[i]*br[j];
    }
    __syncthreads();
  }
  #pragma unroll
  for (int i=0;i<4;i++){
    int r = row0 + ty*4 + i;
    if (r < N)
      *(float4*)(H + (size_t)r*DIM + col0 + tx*4) =
        make_float4(acc[i][0], acc[i][1], acc[i][2], acc[i][3]);
  }
}

// o1 = X@v1, o2 = X@v2 (one wave per row)
__global__ void dgemv_k(const float* __restrict__ X, const float* __restrict__ v1,
                        const float* __restrict__ v2, float* __restrict__ o1,
                        float* __restrict__ o2){
  int gid = blockIdx.x*blockDim.x + threadIdx.x;
  int w = gid >> 6, lane = gid & 63;
  if (w >= NNODE) return;
  const float4* x4 = (const float4*)(X + (size_t)w*DIM);
  float4 xv = x4[lane];
  float4 a = ((const float4*)v1)[lane];
  float4 b = ((const float4*)v2)[lane];
  float s1 = xv.x*a.x + xv.y*a.y + xv.z*a.z + xv.w*a.w;
  float s2 = xv.x*b.x + xv.y*b.y + xv.z*b.z + xv.w*b.w;
  for (int off=32; off; off>>=1){ s1 += __shfl_xor(s1, off); s2 += __shfl_xor(s2, off); }
  if (lane==0){ o1[w] = s1; o2[w] = s2; }
}

// one wave per dst node: segment softmax + weighted gather of h_src rows
__global__ void attn_k(const int* __restrict__ rowptr, const int* __restrict__ srcs,
                       const int* __restrict__ eids, const float* __restrict__ a_s,
                       const float* __restrict__ a_d, const float* __restrict__ ea,
                       const float* __restrict__ wep, const float* __restrict__ hs,
                       const float* __restrict__ bias, const float* __restrict__ xprev,
                       float* __restrict__ xnext, int hasRes){
  int gid = blockIdx.x*blockDim.x + threadIdx.x;
  int w = gid >> 6, lane = gid & 63;
  if (w >= NNODE) return;
  int st = rowptr[w], en = rowptr[w+1];
  float w0 = wep[0], w1 = wep[1];
  float adv = a_d[w];
  float mx = -INFINITY;
  for (int p = st + lane; p < en; p += 64){
    int e = eids[p]; int s = srcs[p];
    float lg = lrelu(a_s[s] + adv + ea[2*e]*w0 + ea[2*e+1]*w1);
    mx = fmaxf(mx, lg);
  }
  for (int off=32; off; off>>=1) mx = fmaxf(mx, __shfl_xor(mx, off));
  float sm = 0.f;
  for (int p = st + lane; p < en; p += 64){
    int e = eids[p]; int s = srcs[p];
    float lg = lrelu(a_s[s] + adv + ea[2*e]*w0 + ea[2*e+1]*w1);
    sm += expf(lg - mx);
  }
  for (int off=32; off; off>>=1) sm += __shfl_xor(sm, off);
  float inv = (en > st) ? 1.f/sm : 0.f;
  float ax=0.f, ay=0.f, az=0.f, aw=0.f;
  const float4* h4 = (const float4*)hs;
  for (int p = st; p < en; ++p){          // all lanes walk segment together
    int e = eids[p]; int s = srcs[p];     // broadcast loads
    float lg = lrelu(a_s[s] + adv + ea[2*e]*w0 + ea[2*e+1]*w1);
    float wgt = expf(lg - mx) * inv;
    float4 hv = h4[(size_t)s*64 + lane];  // coalesced 16B/lane
    ax += wgt*hv.x; ay += wgt*hv.y; az += wgt*hv.z; aw += wgt*hv.w;
  }
  float4 bv = ((const float4*)bias)[lane];
  float4 o;
  o.x = fmaxf(ax + bv.x, 0.f);
  o.y = fmaxf(ay + bv.y, 0.f);
  o.z = fmaxf(az + bv.z, 0.f);
  o.w = fmaxf(aw + bv.w, 0.f);
  if (hasRes){
    float4 r = ((const float4*)xprev)[(size_t)w*64 + lane];
    o.x += r.x; o.y += r.y; o.z += r.z; o.w += r.w;
  }
  ((float4*)xnext)[(size_t)w*64 + lane] = o;
}

__device__ __forceinline__ int lowerb(const int* a, int n, int v){
  int lo=0, hi=n;
  while (lo < hi){ int m = (lo+hi)>>1; if (a[m] < v) lo = m+1; else hi = m; }
  return lo;
}

// batch arrays are sorted -> block per batch, coalesced column sums
__global__ void pool_k(const float* __restrict__ x, const int* __restrict__ batch,
                       float* __restrict__ out){
  int b = blockIdx.x, t = threadIdx.x; // 256
  int st = lowerb(batch, NNODE, b), en = lowerb(batch, NNODE, b+1);
  float s = 0.f;
  for (int i=st;i<en;i++) s += x[(size_t)i*DIM + t];
  out[(size_t)b*DIM + t] = s / fmaxf((float)(en - st), 1.f);
}

__global__ void epool_k(const float* __restrict__ ea, const int* __restrict__ ei,
                        const int* __restrict__ hbatch,
                        const float* __restrict__ Wem, const float* __restrict__ bem,
                        float* __restrict__ epool, float* __restrict__ ecnt){
  int e = blockIdx.x*blockDim.x + threadIdx.x;
  if (e >= EDG) return;
  float e0 = ea[2*e], e1 = ea[2*e+1];
  int b = hbatch[ei[e]];
  atomicAdd(&ecnt[b], 1.f);
  #pragma unroll
  for (int j=0;j<32;j++){
    float v = fmaxf(e0*Wem[j] + e1*Wem[32+j] + bem[j], 0.f);
    atomicAdd(&epool[(size_t)b*32 + j], v);
  }
}

__global__ void head_k(const float* __restrict__ hpool, const float* __restrict__ opool,
                       const float* __restrict__ epool, const float* __restrict__ ecnt,
                       const float* __restrict__ Wp1, const float* __restrict__ bp1,
                       const float* __restrict__ Wp2, const float* __restrict__ bp2,
                       float* __restrict__ out){
  __shared__ float emb[EMBD];
  __shared__ float red[256];
  int b = blockIdx.x, t = threadIdx.x; // 256
  emb[t] = hpool[(size_t)b*DIM + t];
  emb[DIM + t] = opool[(size_t)b*DIM + t];
  if (t < 32) emb[2*DIM + t] = epool[(size_t)b*32 + t] / fmaxf(ecnt[b], 1.f);
  __syncthreads();
  for (int h = 0; h < 2; ++h){
    const float* Wp = h? Wp2 : Wp1;
    const float* bp = h? bp2 : bp1;
    float logit = -INFINITY;
    if (t < CC){
      float s = bp[t];
      for (int k=0;k<EMBD;k++) s += emb[k]*Wp[(size_t)k*CC + t];
      logit = s;
    }
    red[t] = logit; __syncthreads();
    for (int off=128; off; off>>=1){ if (t<off) red[t] = fmaxf(red[t], red[t+off]); __syncthreads(); }
    float mx = red[0]; __syncthreads();
    float ex = (t < CC) ? expf(logit - mx) : 0.f;
    red[t] = ex; __syncthreads();
    for (int off=128; off; off>>=1){ if (t<off) red[t] += red[t+off]; __syncthreads(); }
    float sm = red[0]; __syncthreads();
    if (t < CC) out[((size_t)b*2 + h)*CC + t] = ex / sm;
  }
}

extern "C" void kernel_launch(void* const* d_in, const int* in_sizes, int n_in,
                              void* d_out, int out_size, void* d_ws, size_t ws_size,
                              hipStream_t stream) {
  (void)in_sizes; (void)n_in; (void)out_size; (void)ws_size;
  const float* xh_in   = (const float*)d_in[0];
  const float* xo_in   = (const float*)d_in[1];
  const int*   ei_ho   = (const int*)d_in[2];
  const int*   ei_oh   = (const int*)d_in[3];
  const float* ea_ho   = (const float*)d_in[4];
  const float* ea_oh   = (const float*)d_in[5];
  const int*   hbatch  = (const int*)d_in[6];
  const int*   obatch  = (const int*)d_in[7];
  const float* Wsrc_ho = (const float*)d_in[8];
  const float* Wdst_ho = (const float*)d_in[9];
  const float* asrc_ho = (const float*)d_in[10];
  const float* adst_ho = (const float*)d_in[11];
  const float* Wedge_ho= (const float*)d_in[12];
  const float* aedge_ho= (const float*)d_in[13];
  const float* bias_ho = (const float*)d_in[14];
  const float* Wsrc_oh = (const float*)d_in[15];
  const float* Wdst_oh = (const float*)d_in[16];
  const float* asrc_oh = (const float*)d_in[17];
  const float* adst_oh = (const float*)d_in[18];
  const float* Wedge_oh= (const float*)d_in[19];
  const float* aedge_oh= (const float*)d_in[20];
  const float* bias_oh = (const float*)d_in[21];
  const float* W_emlp  = (const float*)d_in[22];
  const float* b_emlp  = (const float*)d_in[23];
  const float* W_p1    = (const float*)d_in[24];
  const float* b_p1    = (const float*)d_in[25];
  const float* W_p2    = (const float*)d_in[26];
  const float* b_p2    = (const float*)d_in[27];
  float* out = (float*)d_out;

  size_t ND = (size_t)NNODE*DIM;
  float* f = (float*)d_ws;
  float* xh0 = f;
  float* xh1 = f + ND;
  float* xo0 = f + 2*ND;
  float* xo1 = f + 3*ND;
  float* hS  = f + 4*ND;
  float* asho = f + 5*ND;
  float* adho = asho + NNODE;
  float* asoh = adho + NNODE;
  float* adoh = asoh + NNODE;
  float* vbuf = adoh + NNODE;              // 32*256
  float* webuf = vbuf + 32*DIM;            // 32
  float* hpool = webuf + 32;               // BB*DIM
  float* opool = hpool + (size_t)BB*DIM;
  float* epool = opool + (size_t)BB*DIM;   // BB*32
  float* ecnt  = epool + (size_t)BB*32;    // BB
  int* rp_ho  = (int*)(ecnt + BB);
  int* rp_oh  = rp_ho + NNODE + 1;
  int* cnt_ho = rp_oh + NNODE + 1;
  int* cnt_oh = cnt_ho + NNODE;
  int* srcs_ho = cnt_oh + NNODE;
  int* eids_ho = srcs_ho + EDG;
  int* srcs_oh = eids_ho + EDG;
  int* eids_oh = srcs_oh + EDG;

  hipMemsetAsync(cnt_ho, 0, sizeof(int)*2*NNODE, stream);
  hipMemsetAsync(epool, 0, sizeof(float)*(BB*32 + BB), stream);
  vcompute_k<<<2048, 256, 0, stream>>>(Wsrc_ho, Wdst_ho, asrc_ho, adst_ho,
                                       Wsrc_oh, Wdst_oh, asrc_oh, adst_oh, vbuf);
  wecompute_k<<<16, 64, 0, stream>>>(Wedge_ho, aedge_ho, Wedge_oh, aedge_oh, webuf);
  hist_k<<<1954, 256, 0, stream>>>(ei_ho, cnt_ho);
  hist_k<<<1954, 256, 0, stream>>>(ei_oh, cnt_oh);
  scan_k<<<1, 1024, 0, stream>>>(cnt_ho, rp_ho, NNODE);
  scan_k<<<1, 1024, 0, stream>>>(cnt_oh, rp_oh, NNODE);
  hipMemsetAsync(cnt_ho, 0, sizeof(int)*2*NNODE, stream);
  scatter_k<<<1954, 256, 0, stream>>>(ei_ho, rp_ho, cnt_ho, srcs_ho, eids_ho);
  scatter_k<<<1954, 256, 0, stream>>>(ei_oh, rp_oh, cnt_oh, srcs_oh, eids_oh);

  const float* xh = xh_in;
  const float* xo = xo_in;
  float* xh_bufs[2] = {xh0, xh1};
  float* xo_bufs[2] = {xo0, xo1};
  for (int l = 0; l < LAY; ++l){
    float* xo_n = xo_bufs[l & 1];
    float* xh_n = xh_bufs[l & 1];
    // relation ho: src=human, dst=object
    gemm_k<<<3128, 256, 0, stream>>>(xh, Wsrc_ho + (size_t)l*DIM*DIM, hS, NNODE);
    dgemv_k<<<12500, 256, 0, stream>>>(xh, vbuf + (size_t)(l*4+0)*DIM,
                                       vbuf + (size_t)(l*4+3)*DIM, asho, adoh);
    dgemv_k<<<12500, 256, 0, stream>>>(xo, vbuf + (size_t)(l*4+2)*DIM,
                                       vbuf + (size_t)(l*4+1)*DIM, asoh, adho);
    attn_k<<<12500, 256, 0, stream>>>(rp_ho, srcs_ho, eids_ho, asho, adho, ea_ho,
                                      webuf + (size_t)(l*2+0)*2, hS,
                                      bias_ho + (size_t)l*DIM, xo, xo_n, l > 0);
    // relation oh: src=object, dst=human
    gemm_k<<<3128, 256, 0, stream>>>(xo, Wsrc_oh + (size_t)l*DIM*DIM, hS, NNODE);
    attn_k<<<12500, 256, 0, stream>>>(rp_oh, srcs_oh, eids_oh, asoh, adoh, ea_oh,
                                      webuf + (size_t)(l*2+1)*2, hS,
                                      bias_oh + (size_t)l*DIM, xh, xh_n, l > 0);
    xh = xh_n; xo = xo_n;
  }

  pool_k<<<BB, 256, 0, stream>>>(xh, hbatch, hpool);
  pool_k<<<BB, 256, 0, stream>>>(xo, obatch, opool);
  epool_k<<<1954, 256, 0, stream>>>(ea_ho, ei_ho, hbatch, W_emlp, b_emlp, epool, ecnt);
  head_k<<<BB, 256, 0, stream>>>(hpool, opool, epool, ecnt, W_p1, b_p1, W_p2, b_p2, out);
}

// Round 3
// 3664.059 us; speedup vs baseline: 1.4031x; 1.4031x over previous
//
#include <hip/hip_runtime.h>
#include <math.h>

// HELPv3: 8-layer bipartite GAT + pooling + 2 softmax heads.
// R3: R2 minus the bf16 x-mirrors (ws overflow caused R2's crash).
//   - epool via per-src nodeacc + sorted-batch pooled sum (kills atomic contention)
//   - GEMMs: bf16 MFMA 16x16x32, fp32 A converted during LDS staging,
//     fragment-contiguous LDS (conflict-free), H stored bf16 (halves attn gather)
// ws usage ~250MB (R1's 267MB fit).

#define NNODE 50000
#define EDG   500000
#define DIM   256
#define LAY   8
#define BB    512
#define CC    117
#define EMBD  544

typedef short bf16x8 __attribute__((ext_vector_type(8)));
typedef float f32x4  __attribute__((ext_vector_type(4)));

static __device__ __forceinline__ float lrelu(float x){ return x >= 0.f ? x : 0.2f*x; }
static __device__ __forceinline__ unsigned short f2b(float f){
  unsigned int u = __float_as_uint(f);
  unsigned int r = (u + 0x7fffu + ((u >> 16) & 1u)) >> 16;   // RNE
  return (unsigned short)r;
}
static __device__ __forceinline__ float b2f(unsigned short u){
  return __uint_as_float(((unsigned int)u) << 16);
}

// v[k] = sum_j W[k*256+j]*a[j] for 32 (l,rel,which) combos; one wave per output k
__global__ void vcompute_k(const float* __restrict__ Wsho, const float* __restrict__ Wdho,
                           const float* __restrict__ asho, const float* __restrict__ adho,
                           const float* __restrict__ Wsoh, const float* __restrict__ Wdoh,
                           const float* __restrict__ asoh, const float* __restrict__ adoh,
                           float* __restrict__ vbuf){
  int gid = blockIdx.x*blockDim.x + threadIdx.x;
  int wv = gid >> 6, lane = gid & 63;
  if (wv >= 32*DIM) return;
  int p = wv >> 8, k = wv & 255;
  int which = p & 1, rel = (p>>1)&1, l = p>>2;
  const float* W; const float* a;
  if (rel==0){ W = which? Wdho : Wsho; a = which? adho : asho; }
  else       { W = which? Wdoh : Wsoh; a = which? adoh : asoh; }
  W += (size_t)l*DIM*DIM; a += (size_t)l*DIM;
  const float4* w4 = (const float4*)(W + (size_t)k*DIM);
  const float4* a4 = (const float4*)a;
  float4 wv4 = w4[lane], av4 = a4[lane];
  float s = wv4.x*av4.x + wv4.y*av4.y + wv4.z*av4.z + wv4.w*av4.w;
  for (int off=32; off; off>>=1) s += __shfl_xor(s, off);
  if (lane==0) vbuf[(size_t)p*DIM + k] = s;
}

__global__ void wecompute_k(const float* __restrict__ Weho, const float* __restrict__ aeho,
                            const float* __restrict__ Weoh, const float* __restrict__ aeoh,
                            float* __restrict__ webuf){
  int blk = blockIdx.x;            // l*2 + rel
  int rel = blk & 1, l = blk >> 1;
  const float* We = rel? Weoh : Weho;
  const float* ae = rel? aeoh : aeho;
  int lane = threadIdx.x;          // 64
  const float4* w0 = (const float4*)(We + (size_t)l*2*DIM);
  const float4* w1 = (const float4*)(We + (size_t)l*2*DIM + DIM);
  const float4* a4 = (const float4*)(ae + (size_t)l*DIM);
  float4 av = a4[lane], x0 = w0[lane], x1 = w1[lane];
  float s0 = x0.x*av.x + x0.y*av.y + x0.z*av.z + x0.w*av.w;
  float s1 = x1.x*av.x + x1.y*av.y + x1.z*av.z + x1.w*av.w;
  for (int off=32; off; off>>=1){ s0 += __shfl_xor(s0, off); s1 += __shfl_xor(s1, off); }
  if (lane==0){ webuf[blk*2] = s0; webuf[blk*2+1] = s1; }
}

// histogram of row[e] (pass ei for src-hist, ei+EDG for dst-hist)
__global__ void hist_k(const int* __restrict__ row, int* __restrict__ cnt){
  int e = blockIdx.x*blockDim.x + threadIdx.x;
  if (e < EDG) atomicAdd(&cnt[row[e]], 1);
}

__global__ void scan_k(const int* __restrict__ cnt, int* __restrict__ rowptr, int N){
  __shared__ int ps[1024];
  int t = threadIdx.x;
  int CH = (N + 1023) >> 10;
  int base = t*CH;
  int s = 0;
  for (int i=0;i<CH;i++){ int idx=base+i; if (idx<N) s += cnt[idx]; }
  ps[t] = s; __syncthreads();
  for (int off=1; off<1024; off<<=1){
    int v = 0;
    if (t >= off) v = ps[t-off];
    __syncthreads();
    ps[t] += v;
    __syncthreads();
  }
  int run = ps[t] - s;
  for (int i=0;i<CH;i++){ int idx=base+i; if (idx<N){ rowptr[idx] = run; run += cnt[idx]; } }
  if (t == 1023) rowptr[N] = ps[1023];
}

__global__ void scatter_k(const int* __restrict__ ei, const int* __restrict__ rowptr,
                          int* __restrict__ cursor, int* __restrict__ srcs, int* __restrict__ eids){
  int e = blockIdx.x*blockDim.x + threadIdx.x;
  if (e >= EDG) return;
  int d = ei[EDG + e];
  int pos = rowptr[d] + atomicAdd(&cursor[d], 1);
  srcs[pos] = ei[e];
  eids[pos] = e;
}

// Wt[rel][l][n][k] = bf16(W[rel][l][k][n]); total 2*8*65536 elements
__global__ void wtconv_k(const float* __restrict__ Who, const float* __restrict__ Woh,
                         unsigned short* __restrict__ Wt){
  int gid = blockIdx.x*blockDim.x + threadIdx.x;   // < 1048576
  int rel = gid >> 19;
  int rem = gid & ((1<<19)-1);
  int l = rem >> 16;
  int idx = rem & 65535;
  int n = idx >> 8, k = idx & 255;
  const float* W = rel ? Woh : Who;
  Wt[gid] = f2b(W[(size_t)l*65536 + (size_t)k*256 + n]);
}

// H[M,256](bf16) = bf16(A[M,256](fp32)) @ B, Bt[n][k](bf16). 128x128 tile, 4 waves.
// Fragment-contiguous LDS: 16B chunk (group,q,m) at ((grp*4+q)*16+m)*8 shorts.
__global__ __launch_bounds__(256) void gemmb_k(const float* __restrict__ A,
                                               const unsigned short* __restrict__ Bt,
                                               unsigned short* __restrict__ H, int M){
  __shared__ __align__(16) unsigned short As[4096];
  __shared__ __align__(16) unsigned short Bs[4096];
  int tid = threadIdx.x;
  int col0 = blockIdx.x * 128;
  int row0 = blockIdx.y * 128;
  int w = tid >> 6, lane = tid & 63;
  int q = lane >> 4, ml = lane & 15;
  f32x4 acc[2][8];
  #pragma unroll
  for (int i=0;i<2;i++)
    #pragma unroll
    for (int j=0;j<8;j++) acc[i][j] = (f32x4){0.f,0.f,0.f,0.f};
  int srow = tid >> 2;    // 0..63
  int sq   = tid & 3;
  for (int k0 = 0; k0 < 256; k0 += 32){
    #pragma unroll
    for (int p = 0; p < 2; ++p){
      int row = p*64 + srow;
      int gr = row0 + row;
      ushort4 a8[2] = {make_ushort4(0,0,0,0), make_ushort4(0,0,0,0)};
      if (gr < M){
        const float* ap = A + (size_t)gr*256 + k0 + sq*8;
        float4 f0 = *(const float4*)ap;
        float4 f1 = *(const float4*)(ap + 4);
        a8[0] = make_ushort4(f2b(f0.x), f2b(f0.y), f2b(f0.z), f2b(f0.w));
        a8[1] = make_ushort4(f2b(f1.x), f2b(f1.y), f2b(f1.z), f2b(f1.w));
      }
      *(ushort4*)&As[((((row>>4)*4) + sq)*16 + (row&15))*8 + 0] = a8[0];
      *(ushort4*)&As[((((row>>4)*4) + sq)*16 + (row&15))*8 + 4] = a8[1];
      int gc = col0 + row;
      uint4 bv = *(const uint4*)(Bt + (size_t)gc*256 + k0 + sq*8);
      *(uint4*)&Bs[((((row>>4)*4) + sq)*16 + (row&15))*8] = bv;
    }
    __syncthreads();
    bf16x8 a0 = *(const bf16x8*)&As[(((2*w+0)*4 + q)*16 + ml)*8];
    bf16x8 a1 = *(const bf16x8*)&As[(((2*w+1)*4 + q)*16 + ml)*8];
    #pragma unroll
    for (int nf = 0; nf < 8; ++nf){
      bf16x8 b = *(const bf16x8*)&Bs[((nf*4 + q)*16 + ml)*8];
      acc[0][nf] = __builtin_amdgcn_mfma_f32_16x16x32_bf16(a0, b, acc[0][nf], 0,0,0);
      acc[1][nf] = __builtin_amdgcn_mfma_f32_16x16x32_bf16(a1, b, acc[1][nf], 0,0,0);
    }
    __syncthreads();
  }
  #pragma unroll
  for (int mf = 0; mf < 2; ++mf){
    #pragma unroll
    for (int r = 0; r < 4; ++r){
      int gr = row0 + 32*w + 16*mf + q*4 + r;
      if (gr < M){
        #pragma unroll
        for (int nf = 0; nf < 8; ++nf)
          H[(size_t)gr*256 + col0 + nf*16 + ml] = f2b(acc[mf][nf][r]);
      }
    }
  }
}

// o1 = X@v1, o2 = X@v2 (one wave per row), fp32
__global__ void dgemv_k(const float* __restrict__ X, const float* __restrict__ v1,
                        const float* __restrict__ v2, float* __restrict__ o1,
                        float* __restrict__ o2){
  int gid = blockIdx.x*blockDim.x + threadIdx.x;
  int w = gid >> 6, lane = gid & 63;
  if (w >= NNODE) return;
  const float4* x4 = (const float4*)(X + (size_t)w*DIM);
  float4 xv = x4[lane];
  float4 a = ((const float4*)v1)[lane];
  float4 b = ((const float4*)v2)[lane];
  float s1 = xv.x*a.x + xv.y*a.y + xv.z*a.z + xv.w*a.w;
  float s2 = xv.x*b.x + xv.y*b.y + xv.z*b.z + xv.w*b.w;
  for (int off=32; off; off>>=1){ s1 += __shfl_xor(s1, off); s2 += __shfl_xor(s2, off); }
  if (lane==0){ o1[w] = s1; o2[w] = s2; }
}

// one wave per dst node: segment softmax + weighted gather of bf16 h_src rows
__global__ void attn_k(const int* __restrict__ rowptr, const int* __restrict__ srcs,
                       const int* __restrict__ eids, const float* __restrict__ a_s,
                       const float* __restrict__ a_d, const float* __restrict__ ea,
                       const float* __restrict__ wep, const unsigned short* __restrict__ hs,
                       const float* __restrict__ bias, const float* __restrict__ xprev,
                       float* __restrict__ xnext, int hasRes){
  int gid = blockIdx.x*blockDim.x + threadIdx.x;
  int w = gid >> 6, lane = gid & 63;
  if (w >= NNODE) return;
  int st = rowptr[w], en = rowptr[w+1];
  float w0 = wep[0], w1 = wep[1];
  float adv = a_d[w];
  float mx = -INFINITY;
  for (int p = st + lane; p < en; p += 64){
    int e = eids[p]; int s = srcs[p];
    float lg = lrelu(a_s[s] + adv + ea[2*e]*w0 + ea[2*e+1]*w1);
    mx = fmaxf(mx, lg);
  }
  for (int off=32; off; off>>=1) mx = fmaxf(mx, __shfl_xor(mx, off));
  float sm = 0.f;
  for (int p = st + lane; p < en; p += 64){
    int e = eids[p]; int s = srcs[p];
    float lg = lrelu(a_s[s] + adv + ea[2*e]*w0 + ea[2*e+1]*w1);
    sm += expf(lg - mx);
  }
  for (int off=32; off; off>>=1) sm += __shfl_xor(sm, off);
  float inv = (en > st) ? 1.f/sm : 0.f;
  float ax=0.f, ay=0.f, az=0.f, aw=0.f;
  const ushort4* h4 = (const ushort4*)hs;
  for (int p = st; p < en; ++p){
    int e = eids[p]; int s = srcs[p];      // broadcast loads
    float lg = lrelu(a_s[s] + adv + ea[2*e]*w0 + ea[2*e+1]*w1);
    float wgt = expf(lg - mx) * inv;
    ushort4 hv = h4[(size_t)s*64 + lane];  // coalesced 8B/lane
    ax += wgt*b2f(hv.x); ay += wgt*b2f(hv.y); az += wgt*b2f(hv.z); aw += wgt*b2f(hv.w);
  }
  float4 bv = ((const float4*)bias)[lane];
  float4 o;
  o.x = fmaxf(ax + bv.x, 0.f);
  o.y = fmaxf(ay + bv.y, 0.f);
  o.z = fmaxf(az + bv.z, 0.f);
  o.w = fmaxf(aw + bv.w, 0.f);
  if (hasRes){
    float4 r = ((const float4*)xprev)[(size_t)w*64 + lane];
    o.x += r.x; o.y += r.y; o.z += r.z; o.w += r.w;
  }
  ((float4*)xnext)[(size_t)w*64 + lane] = o;
}

__device__ __forceinline__ int lowerb(const int* a, int n, int v){
  int lo=0, hi=n;
  while (lo < hi){ int m = (lo+hi)>>1; if (a[m] < v) lo = m+1; else hi = m; }
  return lo;
}

__global__ void pool_k(const float* __restrict__ x, const int* __restrict__ batch,
                       float* __restrict__ out){
  int b = blockIdx.x, t = threadIdx.x; // 256
  int st = lowerb(batch, NNODE, b), en = lowerb(batch, NNODE, b+1);
  float s = 0.f;
  for (int i=st;i<en;i++) s += x[(size_t)i*DIM + t];
  out[(size_t)b*DIM + t] = s / fmaxf((float)(en - st), 1.f);
}

// edge MLP accumulated per SRC node (1.6M addresses -> low atomic contention)
__global__ void epool1_k(const float* __restrict__ ea, const int* __restrict__ ei,
                         const float* __restrict__ Wem, const float* __restrict__ bem,
                         float* __restrict__ nodeacc){
  __shared__ float w0s[32], w1s[32], bs[32];
  int t = threadIdx.x;
  if (t < 32){ w0s[t]=Wem[t]; w1s[t]=Wem[32+t]; bs[t]=bem[t]; }
  __syncthreads();
  int e = blockIdx.x*256 + t;
  if (e >= EDG) return;
  float e0 = ea[2*e], e1 = ea[2*e+1];
  float* base = nodeacc + (size_t)ei[e]*32;
  #pragma unroll
  for (int j=0;j<32;j++)
    atomicAdd(base + j, fmaxf(e0*w0s[j] + e1*w1s[j] + bs[j], 0.f));
}

// block per batch: coalesced sum of nodeacc rows (hbatch sorted) / edge count
__global__ void epool2_k(const float* __restrict__ nodeacc, const int* __restrict__ outdeg,
                         const int* __restrict__ hbatch, float* __restrict__ epool){
  __shared__ float ps[8][33];
  __shared__ int pd[8];
  int b = blockIdx.x, t = threadIdx.x; // 256
  int j = t & 31, g = t >> 5;
  int st = lowerb(hbatch, NNODE, b), en = lowerb(hbatch, NNODE, b+1);
  float s = 0.f; int d = 0;
  for (int i = st + g; i < en; i += 8){ s += nodeacc[(size_t)i*32 + j]; d += outdeg[i]; }
  ps[g][j] = s;
  if (j == 0) pd[g] = d;
  __syncthreads();
  if (g == 0){
    float tot = 0.f; int cnt = 0;
    #pragma unroll
    for (int gg=0; gg<8; gg++){ tot += ps[gg][j]; cnt += pd[gg]; }
    epool[(size_t)b*32 + j] = tot / fmaxf((float)cnt, 1.f);
  }
}

__global__ void head_k(const float* __restrict__ hpool, const float* __restrict__ opool,
                       const float* __restrict__ epool,
                       const float* __restrict__ Wp1, const float* __restrict__ bp1,
                       const float* __restrict__ Wp2, const float* __restrict__ bp2,
                       float* __restrict__ out){
  __shared__ float emb[EMBD];
  __shared__ float red[256];
  int b = blockIdx.x, t = threadIdx.x; // 256
  emb[t] = hpool[(size_t)b*DIM + t];
  emb[DIM + t] = opool[(size_t)b*DIM + t];
  if (t < 32) emb[2*DIM + t] = epool[(size_t)b*32 + t];
  __syncthreads();
  for (int h = 0; h < 2; ++h){
    const float* Wp = h? Wp2 : Wp1;
    const float* bp = h? bp2 : bp1;
    float logit = -INFINITY;
    if (t < CC){
      float s = bp[t];
      for (int k=0;k<EMBD;k++) s += emb[k]*Wp[(size_t)k*CC + t];
      logit = s;
    }
    red[t] = logit; __syncthreads();
    for (int off=128; off; off>>=1){ if (t<off) red[t] = fmaxf(red[t], red[t+off]); __syncthreads(); }
    float mx = red[0]; __syncthreads();
    float ex = (t < CC) ? expf(logit - mx) : 0.f;
    red[t] = ex; __syncthreads();
    for (int off=128; off; off>>=1){ if (t<off) red[t] += red[t+off]; __syncthreads(); }
    float sm = red[0]; __syncthreads();
    if (t < CC) out[((size_t)b*2 + h)*CC + t] = ex / sm;
  }
}

extern "C" void kernel_launch(void* const* d_in, const int* in_sizes, int n_in,
                              void* d_out, int out_size, void* d_ws, size_t ws_size,
                              hipStream_t stream) {
  (void)in_sizes; (void)n_in; (void)out_size; (void)ws_size;
  const float* xh_in   = (const float*)d_in[0];
  const float* xo_in   = (const float*)d_in[1];
  const int*   ei_ho   = (const int*)d_in[2];
  const int*   ei_oh   = (const int*)d_in[3];
  const float* ea_ho   = (const float*)d_in[4];
  const float* ea_oh   = (const float*)d_in[5];
  const int*   hbatch  = (const int*)d_in[6];
  const int*   obatch  = (const int*)d_in[7];
  const float* Wsrc_ho = (const float*)d_in[8];
  const float* Wdst_ho = (const float*)d_in[9];
  const float* asrc_ho = (const float*)d_in[10];
  const float* adst_ho = (const float*)d_in[11];
  const float* Wedge_ho= (const float*)d_in[12];
  const float* aedge_ho= (const float*)d_in[13];
  const float* bias_ho = (const float*)d_in[14];
  const float* Wsrc_oh = (const float*)d_in[15];
  const float* Wdst_oh = (const float*)d_in[16];
  const float* asrc_oh = (const float*)d_in[17];
  const float* adst_oh = (const float*)d_in[18];
  const float* Wedge_oh= (const float*)d_in[19];
  const float* aedge_oh= (const float*)d_in[20];
  const float* bias_oh = (const float*)d_in[21];
  const float* W_emlp  = (const float*)d_in[22];
  const float* b_emlp  = (const float*)d_in[23];
  const float* W_p1    = (const float*)d_in[24];
  const float* b_p1    = (const float*)d_in[25];
  const float* W_p2    = (const float*)d_in[26];
  const float* b_p2    = (const float*)d_in[27];
  float* out = (float*)d_out;

  size_t ND = (size_t)NNODE*DIM;
  float* f = (float*)d_ws;
  float* xh0 = f;
  float* xh1 = f + ND;
  float* xo0 = f + 2*ND;
  float* xo1 = f + 3*ND;
  float* asho = f + 4*ND;
  float* adho = asho + NNODE;
  float* asoh = adho + NNODE;
  float* adoh = asoh + NNODE;
  float* vbuf  = adoh + NNODE;             // 32*256
  float* webuf = vbuf + 32*DIM;            // 32
  float* hpool = webuf + 32;               // BB*DIM
  float* opool = hpool + (size_t)BB*DIM;
  float* epool = opool + (size_t)BB*DIM;   // BB*32
  float* nodeacc = epool + (size_t)BB*32;  // NNODE*32
  unsigned short* hSb = (unsigned short*)(nodeacc + (size_t)NNODE*32);  // ND bf16
  unsigned short* Wtb = hSb + ND;          // 2*8*65536 bf16
  int* cnt_ho = (int*)(Wtb + (size_t)2*LAY*DIM*DIM);
  int* cnt_oh = cnt_ho + NNODE;
  int* outdeg = cnt_oh + NNODE;
  int* rp_ho  = outdeg + NNODE;
  int* rp_oh  = rp_ho + NNODE + 1;
  int* srcs_ho = rp_oh + NNODE + 1;
  int* eids_ho = srcs_ho + EDG;
  int* srcs_oh = eids_ho + EDG;
  int* eids_oh = srcs_oh + EDG;

  hipMemsetAsync(cnt_ho, 0, sizeof(int)*3*NNODE, stream);            // cnt_ho,cnt_oh,outdeg
  hipMemsetAsync(nodeacc, 0, sizeof(float)*(size_t)NNODE*32, stream);
  vcompute_k<<<2048, 256, 0, stream>>>(Wsrc_ho, Wdst_ho, asrc_ho, adst_ho,
                                       Wsrc_oh, Wdst_oh, asrc_oh, adst_oh, vbuf);
  wecompute_k<<<16, 64, 0, stream>>>(Wedge_ho, aedge_ho, Wedge_oh, aedge_oh, webuf);
  wtconv_k<<<4096, 256, 0, stream>>>(Wsrc_ho, Wsrc_oh, Wtb);
  hist_k<<<1954, 256, 0, stream>>>(ei_ho + EDG, cnt_ho);
  hist_k<<<1954, 256, 0, stream>>>(ei_oh + EDG, cnt_oh);
  hist_k<<<1954, 256, 0, stream>>>(ei_ho, outdeg);                   // src outdegree
  scan_k<<<1, 1024, 0, stream>>>(cnt_ho, rp_ho, NNODE);
  scan_k<<<1, 1024, 0, stream>>>(cnt_oh, rp_oh, NNODE);
  hipMemsetAsync(cnt_ho, 0, sizeof(int)*2*NNODE, stream);
  scatter_k<<<1954, 256, 0, stream>>>(ei_ho, rp_ho, cnt_ho, srcs_ho, eids_ho);
  scatter_k<<<1954, 256, 0, stream>>>(ei_oh, rp_oh, cnt_oh, srcs_oh, eids_oh);
  epool1_k<<<1954, 256, 0, stream>>>(ea_ho, ei_ho, W_emlp, b_emlp, nodeacc);

  const float* xh = xh_in;
  const float* xo = xo_in;
  float* xh_bufs[2] = {xh0, xh1};
  float* xo_bufs[2] = {xo0, xo1};
  for (int l = 0; l < LAY; ++l){
    float* xo_n = xo_bufs[l & 1];
    float* xh_n = xh_bufs[l & 1];
    // relation ho: src=human, dst=object
    gemmb_k<<<dim3(2, 391), 256, 0, stream>>>(xh, Wtb + (size_t)l*DIM*DIM, hSb, NNODE);
    dgemv_k<<<12500, 256, 0, stream>>>(xh, vbuf + (size_t)(l*4+0)*DIM,
                                       vbuf + (size_t)(l*4+3)*DIM, asho, adoh);
    dgemv_k<<<12500, 256, 0, stream>>>(xo, vbuf + (size_t)(l*4+2)*DIM,
                                       vbuf + (size_t)(l*4+1)*DIM, asoh, adho);
    attn_k<<<12500, 256, 0, stream>>>(rp_ho, srcs_ho, eids_ho, asho, adho, ea_ho,
                                      webuf + (size_t)(l*2+0)*2, hSb,
                                      bias_ho + (size_t)l*DIM, xo, xo_n, l > 0);
    // relation oh: src=object, dst=human
    gemmb_k<<<dim3(2, 391), 256, 0, stream>>>(xo, Wtb + (size_t)(LAY + l)*DIM*DIM, hSb, NNODE);
    attn_k<<<12500, 256, 0, stream>>>(rp_oh, srcs_oh, eids_oh, asoh, adoh, ea_oh,
                                      webuf + (size_t)(l*2+1)*2, hSb,
                                      bias_oh + (size_t)l*DIM, xh, xh_n, l > 0);
    xh = xh_n; xo = xo_n;
  }

  pool_k<<<BB, 256, 0, stream>>>(xh, hbatch, hpool);
  pool_k<<<BB, 256, 0, stream>>>(xo, obatch, opool);
  epool2_k<<<BB, 256, 0, stream>>>(nodeacc, outdeg, hbatch, epool);
  head_k<<<BB, 256, 0, stream>>>(hpool, opool, epool, W_p1, b_p1, W_p2, b_p2, out);
}

// Round 4
// 2875.961 us; speedup vs baseline: 1.7876x; 1.2740x over previous
//
#include <hip/hip_runtime.h>
#include <math.h>

// HELPv3: 8-layer bipartite GAT + pooling + 2 softmax heads.
// R4: kill the 16M-float-atomic epool (820us, 500MB HBM writes):
//   src-sorted CSR => per-batch edges contiguous => fused atomic-free epool.
//   Also: edge attrs permuted by dst (eaperm) so attn reads them coalesced.
// Carried: bf16 MFMA GEMM (fragment-contiguous LDS), bf16 H, atomic-free attn CSR.

#define NNODE 50000
#define EDG   500000
#define DIM   256
#define LAY   8
#define BB    512
#define CC    117
#define EMBD  544

typedef short bf16x8 __attribute__((ext_vector_type(8)));
typedef float f32x4  __attribute__((ext_vector_type(4)));

static __device__ __forceinline__ float lrelu(float x){ return x >= 0.f ? x : 0.2f*x; }
static __device__ __forceinline__ unsigned short f2b(float f){
  unsigned int u = __float_as_uint(f);
  unsigned int r = (u + 0x7fffu + ((u >> 16) & 1u)) >> 16;   // RNE
  return (unsigned short)r;
}
static __device__ __forceinline__ float b2f(unsigned short u){
  return __uint_as_float(((unsigned int)u) << 16);
}

// v[k] = sum_j W[k*256+j]*a[j] for 32 (l,rel,which) combos; one wave per output k
__global__ void vcompute_k(const float* __restrict__ Wsho, const float* __restrict__ Wdho,
                           const float* __restrict__ asho, const float* __restrict__ adho,
                           const float* __restrict__ Wsoh, const float* __restrict__ Wdoh,
                           const float* __restrict__ asoh, const float* __restrict__ adoh,
                           float* __restrict__ vbuf){
  int gid = blockIdx.x*blockDim.x + threadIdx.x;
  int wv = gid >> 6, lane = gid & 63;
  if (wv >= 32*DIM) return;
  int p = wv >> 8, k = wv & 255;
  int which = p & 1, rel = (p>>1)&1, l = p>>2;
  const float* W; const float* a;
  if (rel==0){ W = which? Wdho : Wsho; a = which? adho : asho; }
  else       { W = which? Wdoh : Wsoh; a = which? adoh : asoh; }
  W += (size_t)l*DIM*DIM; a += (size_t)l*DIM;
  const float4* w4 = (const float4*)(W + (size_t)k*DIM);
  const float4* a4 = (const float4*)a;
  float4 wv4 = w4[lane], av4 = a4[lane];
  float s = wv4.x*av4.x + wv4.y*av4.y + wv4.z*av4.z + wv4.w*av4.w;
  for (int off=32; off; off>>=1) s += __shfl_xor(s, off);
  if (lane==0) vbuf[(size_t)p*DIM + k] = s;
}

__global__ void wecompute_k(const float* __restrict__ Weho, const float* __restrict__ aeho,
                            const float* __restrict__ Weoh, const float* __restrict__ aeoh,
                            float* __restrict__ webuf){
  int blk = blockIdx.x;            // l*2 + rel
  int rel = blk & 1, l = blk >> 1;
  const float* We = rel? Weoh : Weho;
  const float* ae = rel? aeoh : aeho;
  int lane = threadIdx.x;          // 64
  const float4* w0 = (const float4*)(We + (size_t)l*2*DIM);
  const float4* w1 = (const float4*)(We + (size_t)l*2*DIM + DIM);
  const float4* a4 = (const float4*)(ae + (size_t)l*DIM);
  float4 av = a4[lane], x0 = w0[lane], x1 = w1[lane];
  float s0 = x0.x*av.x + x0.y*av.y + x0.z*av.z + x0.w*av.w;
  float s1 = x1.x*av.x + x1.y*av.y + x1.z*av.z + x1.w*av.w;
  for (int off=32; off; off>>=1){ s0 += __shfl_xor(s0, off); s1 += __shfl_xor(s1, off); }
  if (lane==0){ webuf[blk*2] = s0; webuf[blk*2+1] = s1; }
}

// histogram of row[e]
__global__ void hist_k(const int* __restrict__ row, int* __restrict__ cnt){
  int e = blockIdx.x*blockDim.x + threadIdx.x;
  if (e < EDG) atomicAdd(&cnt[row[e]], 1);
}

__global__ void scan_k(const int* __restrict__ cnt, int* __restrict__ rowptr, int N){
  __shared__ int ps[1024];
  int t = threadIdx.x;
  int CH = (N + 1023) >> 10;
  int base = t*CH;
  int s = 0;
  for (int i=0;i<CH;i++){ int idx=base+i; if (idx<N) s += cnt[idx]; }
  ps[t] = s; __syncthreads();
  for (int off=1; off<1024; off<<=1){
    int v = 0;
    if (t >= off) v = ps[t-off];
    __syncthreads();
    ps[t] += v;
    __syncthreads();
  }
  int run = ps[t] - s;
  for (int i=0;i<CH;i++){ int idx=base+i; if (idx<N){ rowptr[idx] = run; run += cnt[idx]; } }
  if (t == 1023) rowptr[N] = ps[1023];
}

// dst-CSR scatter: srcs + permuted edge attrs
__global__ void scatter_k(const int* __restrict__ ei, const float* __restrict__ ea,
                          const int* __restrict__ rowptr, int* __restrict__ cursor,
                          int* __restrict__ srcs, float2* __restrict__ eaperm){
  int e = blockIdx.x*blockDim.x + threadIdx.x;
  if (e >= EDG) return;
  int d = ei[EDG + e];
  int pos = rowptr[d] + atomicAdd(&cursor[d], 1);
  srcs[pos] = ei[e];
  eaperm[pos] = make_float2(ea[2*e], ea[2*e+1]);
}

// src-CSR scatter (ho only): permuted edge attrs for epool
__global__ void scatter_src_k(const int* __restrict__ ei, const float* __restrict__ ea,
                              const int* __restrict__ rowptr, int* __restrict__ cursor,
                              float2* __restrict__ eaperm){
  int e = blockIdx.x*blockDim.x + threadIdx.x;
  if (e >= EDG) return;
  int s = ei[e];
  int pos = rowptr[s] + atomicAdd(&cursor[s], 1);
  eaperm[pos] = make_float2(ea[2*e], ea[2*e+1]);
}

// Wt[rel][l][n][k] = bf16(W[rel][l][k][n])
__global__ void wtconv_k(const float* __restrict__ Who, const float* __restrict__ Woh,
                         unsigned short* __restrict__ Wt){
  int gid = blockIdx.x*blockDim.x + threadIdx.x;   // < 1048576
  int rel = gid >> 19;
  int rem = gid & ((1<<19)-1);
  int l = rem >> 16;
  int idx = rem & 65535;
  int n = idx >> 8, k = idx & 255;
  const float* W = rel ? Woh : Who;
  Wt[gid] = f2b(W[(size_t)l*65536 + (size_t)k*256 + n]);
}

// H[M,256](bf16) = bf16(A[M,256](fp32)) @ B, Bt[n][k](bf16). 128x128 tile, 4 waves.
__global__ __launch_bounds__(256) void gemmb_k(const float* __restrict__ A,
                                               const unsigned short* __restrict__ Bt,
                                               unsigned short* __restrict__ H, int M){
  __shared__ __align__(16) unsigned short As[4096];
  __shared__ __align__(16) unsigned short Bs[4096];
  int tid = threadIdx.x;
  int col0 = blockIdx.x * 128;
  int row0 = blockIdx.y * 128;
  int w = tid >> 6, lane = tid & 63;
  int q = lane >> 4, ml = lane & 15;
  f32x4 acc[2][8];
  #pragma unroll
  for (int i=0;i<2;i++)
    #pragma unroll
    for (int j=0;j<8;j++) acc[i][j] = (f32x4){0.f,0.f,0.f,0.f};
  int srow = tid >> 2;    // 0..63
  int sq   = tid & 3;
  for (int k0 = 0; k0 < 256; k0 += 32){
    #pragma unroll
    for (int p = 0; p < 2; ++p){
      int row = p*64 + srow;
      int gr = row0 + row;
      ushort4 a8[2] = {make_ushort4(0,0,0,0), make_ushort4(0,0,0,0)};
      if (gr < M){
        const float* ap = A + (size_t)gr*256 + k0 + sq*8;
        float4 f0 = *(const float4*)ap;
        float4 f1 = *(const float4*)(ap + 4);
        a8[0] = make_ushort4(f2b(f0.x), f2b(f0.y), f2b(f0.z), f2b(f0.w));
        a8[1] = make_ushort4(f2b(f1.x), f2b(f1.y), f2b(f1.z), f2b(f1.w));
      }
      *(ushort4*)&As[((((row>>4)*4) + sq)*16 + (row&15))*8 + 0] = a8[0];
      *(ushort4*)&As[((((row>>4)*4) + sq)*16 + (row&15))*8 + 4] = a8[1];
      int gc = col0 + row;
      uint4 bv = *(const uint4*)(Bt + (size_t)gc*256 + k0 + sq*8);
      *(uint4*)&Bs[((((row>>4)*4) + sq)*16 + (row&15))*8] = bv;
    }
    __syncthreads();
    bf16x8 a0 = *(const bf16x8*)&As[(((2*w+0)*4 + q)*16 + ml)*8];
    bf16x8 a1 = *(const bf16x8*)&As[(((2*w+1)*4 + q)*16 + ml)*8];
    #pragma unroll
    for (int nf = 0; nf < 8; ++nf){
      bf16x8 b = *(const bf16x8*)&Bs[((nf*4 + q)*16 + ml)*8];
      acc[0][nf] = __builtin_amdgcn_mfma_f32_16x16x32_bf16(a0, b, acc[0][nf], 0,0,0);
      acc[1][nf] = __builtin_amdgcn_mfma_f32_16x16x32_bf16(a1, b, acc[1][nf], 0,0,0);
    }
    __syncthreads();
  }
  #pragma unroll
  for (int mf = 0; mf < 2; ++mf){
    #pragma unroll
    for (int r = 0; r < 4; ++r){
      int gr = row0 + 32*w + 16*mf + q*4 + r;
      if (gr < M){
        #pragma unroll
        for (int nf = 0; nf < 8; ++nf)
          H[(size_t)gr*256 + col0 + nf*16 + ml] = f2b(acc[mf][nf][r]);
      }
    }
  }
}

// o1 = X@v1, o2 = X@v2 (one wave per row), fp32
__global__ void dgemv_k(const float* __restrict__ X, const float* __restrict__ v1,
                        const float* __restrict__ v2, float* __restrict__ o1,
                        float* __restrict__ o2){
  int gid = blockIdx.x*blockDim.x + threadIdx.x;
  int w = gid >> 6, lane = gid & 63;
  if (w >= NNODE) return;
  const float4* x4 = (const float4*)(X + (size_t)w*DIM);
  float4 xv = x4[lane];
  float4 a = ((const float4*)v1)[lane];
  float4 b = ((const float4*)v2)[lane];
  float s1 = xv.x*a.x + xv.y*a.y + xv.z*a.z + xv.w*a.w;
  float s2 = xv.x*b.x + xv.y*b.y + xv.z*b.z + xv.w*b.w;
  for (int off=32; off; off>>=1){ s1 += __shfl_xor(s1, off); s2 += __shfl_xor(s2, off); }
  if (lane==0){ o1[w] = s1; o2[w] = s2; }
}

// one wave per dst node: segment softmax + weighted gather of bf16 h_src rows
__global__ void attn_k(const int* __restrict__ rowptr, const int* __restrict__ srcs,
                       const float2* __restrict__ eaperm, const float* __restrict__ a_s,
                       const float* __restrict__ a_d,
                       const float* __restrict__ wep, const unsigned short* __restrict__ hs,
                       const float* __restrict__ bias, const float* __restrict__ xprev,
                       float* __restrict__ xnext, int hasRes){
  int gid = blockIdx.x*blockDim.x + threadIdx.x;
  int w = gid >> 6, lane = gid & 63;
  if (w >= NNODE) return;
  int st = rowptr[w], en = rowptr[w+1];
  float w0 = wep[0], w1 = wep[1];
  float adv = a_d[w];
  float mx = -INFINITY;
  for (int p = st + lane; p < en; p += 64){
    float2 ev = eaperm[p];
    float lg = lrelu(a_s[srcs[p]] + adv + ev.x*w0 + ev.y*w1);
    mx = fmaxf(mx, lg);
  }
  for (int off=32; off; off>>=1) mx = fmaxf(mx, __shfl_xor(mx, off));
  float sm = 0.f;
  for (int p = st + lane; p < en; p += 64){
    float2 ev = eaperm[p];
    float lg = lrelu(a_s[srcs[p]] + adv + ev.x*w0 + ev.y*w1);
    sm += expf(lg - mx);
  }
  for (int off=32; off; off>>=1) sm += __shfl_xor(sm, off);
  float inv = (en > st) ? 1.f/sm : 0.f;
  float ax=0.f, ay=0.f, az=0.f, aw=0.f;
  const ushort4* h4 = (const ushort4*)hs;
  for (int p = st; p < en; ++p){
    float2 ev = eaperm[p];                 // broadcast
    int s = srcs[p];
    float lg = lrelu(a_s[s] + adv + ev.x*w0 + ev.y*w1);
    float wgt = expf(lg - mx) * inv;
    ushort4 hv = h4[(size_t)s*64 + lane];  // coalesced 8B/lane
    ax += wgt*b2f(hv.x); ay += wgt*b2f(hv.y); az += wgt*b2f(hv.z); aw += wgt*b2f(hv.w);
  }
  float4 bv = ((const float4*)bias)[lane];
  float4 o;
  o.x = fmaxf(ax + bv.x, 0.f);
  o.y = fmaxf(ay + bv.y, 0.f);
  o.z = fmaxf(az + bv.z, 0.f);
  o.w = fmaxf(aw + bv.w, 0.f);
  if (hasRes){
    float4 r = ((const float4*)xprev)[(size_t)w*64 + lane];
    o.x += r.x; o.y += r.y; o.z += r.z; o.w += r.w;
  }
  ((float4*)xnext)[(size_t)w*64 + lane] = o;
}

__device__ __forceinline__ int lowerb(const int* a, int n, int v){
  int lo=0, hi=n;
  while (lo < hi){ int m = (lo+hi)>>1; if (a[m] < v) lo = m+1; else hi = m; }
  return lo;
}

__global__ void pool_k(const float* __restrict__ x, const int* __restrict__ batch,
                       float* __restrict__ out){
  int b = blockIdx.x, t = threadIdx.x; // 256
  int st = lowerb(batch, NNODE, b), en = lowerb(batch, NNODE, b+1);
  float s = 0.f;
  for (int i=st;i<en;i++) s += x[(size_t)i*DIM + t];
  out[(size_t)b*DIM + t] = s / fmaxf((float)(en - st), 1.f);
}

// fused edge-MLP pool: hbatch sorted + src-CSR => batch b's edges are the
// contiguous range [rp_src[node_lo], rp_src[node_hi]). No atomics.
__global__ void epool_k(const int* __restrict__ rp_src, const int* __restrict__ hbatch,
                        const float2* __restrict__ eaperm, const float* __restrict__ Wem,
                        const float* __restrict__ bem, float* __restrict__ epool){
  __shared__ float ps[8][33];
  int b = blockIdx.x, t = threadIdx.x; // 256
  int j = t & 31, g = t >> 5;
  int nst = lowerb(hbatch, NNODE, b), nen = lowerb(hbatch, NNODE, b+1);
  int est = rp_src[nst], een = rp_src[nen];
  float w0 = Wem[j], w1 = Wem[32+j], bb = bem[j];
  float s = 0.f;
  for (int p = est + g; p < een; p += 8){
    float2 e = eaperm[p];
    s += fmaxf(e.x*w0 + e.y*w1 + bb, 0.f);
  }
  ps[g][j] = s; __syncthreads();
  if (g == 0){
    float tot = 0.f;
    #pragma unroll
    for (int gg=0; gg<8; gg++) tot += ps[gg][j];
    epool[(size_t)b*32 + j] = tot / fmaxf((float)(een - est), 1.f);
  }
}

__global__ void head_k(const float* __restrict__ hpool, const float* __restrict__ opool,
                       const float* __restrict__ epool,
                       const float* __restrict__ Wp1, const float* __restrict__ bp1,
                       const float* __restrict__ Wp2, const float* __restrict__ bp2,
                       float* __restrict__ out){
  __shared__ float emb[EMBD];
  __shared__ float red[256];
  int b = blockIdx.x, t = threadIdx.x; // 256
  emb[t] = hpool[(size_t)b*DIM + t];
  emb[DIM + t] = opool[(size_t)b*DIM + t];
  if (t < 32) emb[2*DIM + t] = epool[(size_t)b*32 + t];
  __syncthreads();
  for (int h = 0; h < 2; ++h){
    const float* Wp = h? Wp2 : Wp1;
    const float* bp = h? bp2 : bp1;
    float logit = -INFINITY;
    if (t < CC){
      float s = bp[t];
      for (int k=0;k<EMBD;k++) s += emb[k]*Wp[(size_t)k*CC + t];
      logit = s;
    }
    red[t] = logit; __syncthreads();
    for (int off=128; off; off>>=1){ if (t<off) red[t] = fmaxf(red[t], red[t+off]); __syncthreads(); }
    float mx = red[0]; __syncthreads();
    float ex = (t < CC) ? expf(logit - mx) : 0.f;
    red[t] = ex; __syncthreads();
    for (int off=128; off; off>>=1){ if (t<off) red[t] += red[t+off]; __syncthreads(); }
    float sm = red[0]; __syncthreads();
    if (t < CC) out[((size_t)b*2 + h)*CC + t] = ex / sm;
  }
}

extern "C" void kernel_launch(void* const* d_in, const int* in_sizes, int n_in,
                              void* d_out, int out_size, void* d_ws, size_t ws_size,
                              hipStream_t stream) {
  (void)in_sizes; (void)n_in; (void)out_size; (void)ws_size;
  const float* xh_in   = (const float*)d_in[0];
  const float* xo_in   = (const float*)d_in[1];
  const int*   ei_ho   = (const int*)d_in[2];
  const int*   ei_oh   = (const int*)d_in[3];
  const float* ea_ho   = (const float*)d_in[4];
  const float* ea_oh   = (const float*)d_in[5];
  const int*   hbatch  = (const int*)d_in[6];
  const int*   obatch  = (const int*)d_in[7];
  const float* Wsrc_ho = (const float*)d_in[8];
  const float* Wdst_ho = (const float*)d_in[9];
  const float* asrc_ho = (const float*)d_in[10];
  const float* adst_ho = (const float*)d_in[11];
  const float* Wedge_ho= (const float*)d_in[12];
  const float* aedge_ho= (const float*)d_in[13];
  const float* bias_ho = (const float*)d_in[14];
  const float* Wsrc_oh = (const float*)d_in[15];
  const float* Wdst_oh = (const float*)d_in[16];
  const float* asrc_oh = (const float*)d_in[17];
  const float* adst_oh = (const float*)d_in[18];
  const float* Wedge_oh= (const float*)d_in[19];
  const float* aedge_oh= (const float*)d_in[20];
  const float* bias_oh = (const float*)d_in[21];
  const float* W_emlp  = (const float*)d_in[22];
  const float* b_emlp  = (const float*)d_in[23];
  const float* W_p1    = (const float*)d_in[24];
  const float* b_p1    = (const float*)d_in[25];
  const float* W_p2    = (const float*)d_in[26];
  const float* b_p2    = (const float*)d_in[27];
  float* out = (float*)d_out;

  size_t ND = (size_t)NNODE*DIM;
  float* f = (float*)d_ws;
  float* xh0 = f;
  float* xh1 = f + ND;
  float* xo0 = f + 2*ND;
  float* xo1 = f + 3*ND;
  float* asho = f + 4*ND;
  float* adho = asho + NNODE;
  float* asoh = adho + NNODE;
  float* adoh = asoh + NNODE;
  float* vbuf  = adoh + NNODE;             // 32*256
  float* webuf = vbuf + 32*DIM;            // 32
  float* hpool = webuf + 32;               // BB*DIM
  float* opool = hpool + (size_t)BB*DIM;
  float* epool = opool + (size_t)BB*DIM;   // BB*32
  float2* eap_ho  = (float2*)(epool + (size_t)BB*32);   // E float2
  float2* eap_oh  = eap_ho + EDG;
  float2* eap_src = eap_oh + EDG;
  unsigned short* hSb = (unsigned short*)(eap_src + EDG);  // ND bf16
  unsigned short* Wtb = hSb + ND;          // 2*8*65536 bf16
  int* cnt_ho  = (int*)(Wtb + (size_t)2*LAY*DIM*DIM);
  int* cnt_oh  = cnt_ho + NNODE;
  int* cnt_src = cnt_oh + NNODE;
  int* rp_ho   = cnt_src + NNODE;
  int* rp_oh   = rp_ho + NNODE + 1;
  int* rp_src  = rp_oh + NNODE + 1;
  int* srcs_ho = rp_src + NNODE + 1;
  int* srcs_oh = srcs_ho + EDG;

  hipMemsetAsync(cnt_ho, 0, sizeof(int)*3*NNODE, stream);
  vcompute_k<<<2048, 256, 0, stream>>>(Wsrc_ho, Wdst_ho, asrc_ho, adst_ho,
                                       Wsrc_oh, Wdst_oh, asrc_oh, adst_oh, vbuf);
  wecompute_k<<<16, 64, 0, stream>>>(Wedge_ho, aedge_ho, Wedge_oh, aedge_oh, webuf);
  wtconv_k<<<4096, 256, 0, stream>>>(Wsrc_ho, Wsrc_oh, Wtb);
  hist_k<<<1954, 256, 0, stream>>>(ei_ho + EDG, cnt_ho);
  hist_k<<<1954, 256, 0, stream>>>(ei_oh + EDG, cnt_oh);
  hist_k<<<1954, 256, 0, stream>>>(ei_ho, cnt_src);                  // src histogram
  scan_k<<<1, 1024, 0, stream>>>(cnt_ho, rp_ho, NNODE);
  scan_k<<<1, 1024, 0, stream>>>(cnt_oh, rp_oh, NNODE);
  scan_k<<<1, 1024, 0, stream>>>(cnt_src, rp_src, NNODE);
  hipMemsetAsync(cnt_ho, 0, sizeof(int)*3*NNODE, stream);            // reuse as cursors
  scatter_k<<<1954, 256, 0, stream>>>(ei_ho, ea_ho, rp_ho, cnt_ho, srcs_ho, eap_ho);
  scatter_k<<<1954, 256, 0, stream>>>(ei_oh, ea_oh, rp_oh, cnt_oh, srcs_oh, eap_oh);
  scatter_src_k<<<1954, 256, 0, stream>>>(ei_ho, ea_ho, rp_src, cnt_src, eap_src);

  const float* xh = xh_in;
  const float* xo = xo_in;
  float* xh_bufs[2] = {xh0, xh1};
  float* xo_bufs[2] = {xo0, xo1};
  for (int l = 0; l < LAY; ++l){
    float* xo_n = xo_bufs[l & 1];
    float* xh_n = xh_bufs[l & 1];
    // relation ho: src=human, dst=object
    gemmb_k<<<dim3(2, 391), 256, 0, stream>>>(xh, Wtb + (size_t)l*DIM*DIM, hSb, NNODE);
    dgemv_k<<<12500, 256, 0, stream>>>(xh, vbuf + (size_t)(l*4+0)*DIM,
                                       vbuf + (size_t)(l*4+3)*DIM, asho, adoh);
    dgemv_k<<<12500, 256, 0, stream>>>(xo, vbuf + (size_t)(l*4+2)*DIM,
                                       vbuf + (size_t)(l*4+1)*DIM, asoh, adho);
    attn_k<<<12500, 256, 0, stream>>>(rp_ho, srcs_ho, eap_ho, asho, adho,
                                      webuf + (size_t)(l*2+0)*2, hSb,
                                      bias_ho + (size_t)l*DIM, xo, xo_n, l > 0);
    // relation oh: src=object, dst=human
    gemmb_k<<<dim3(2, 391), 256, 0, stream>>>(xo, Wtb + (size_t)(LAY + l)*DIM*DIM, hSb, NNODE);
    attn_k<<<12500, 256, 0, stream>>>(rp_oh, srcs_oh, eap_oh, asoh, adoh,
                                      webuf + (size_t)(l*2+1)*2, hSb,
                                      bias_oh + (size_t)l*DIM, xh, xh_n, l > 0);
    xh = xh_n; xo = xo_n;
  }

  pool_k<<<BB, 256, 0, stream>>>(xh, hbatch, hpool);
  pool_k<<<BB, 256, 0, stream>>>(xo, obatch, opool);
  epool_k<<<BB, 256, 0, stream>>>(rp_src, hbatch, eap_src, W_emlp, b_emlp, epool);
  head_k<<<BB, 256, 0, stream>>>(hpool, opool, epool, W_p1, b_p1, W_p2, b_p2, out);
}

// Round 5
// 2093.331 us; speedup vs baseline: 2.4560x; 1.3739x over previous
//
#include <hip/hip_runtime.h>
#include <math.h>

// HELPv3: 8-layer bipartite GAT + pooling + 2 softmax heads.
// R5: (1) hierarchical 3-array scan (was 3x95us single-block scans)
//     (2) attn lane-per-edge fast path (deg<=64), deg>64 fallback
//     (3) next-layer a_s/a_d dots fused into attn epilogue (kills 14/16 dgemv)
//     (4) hist x3 fused into one launch
// Carried: bf16 MFMA GEMM, bf16 H, dst/src CSRs with permuted edge attrs.

#define NNODE 50000
#define EDG   500000
#define DIM   256
#define LAY   8
#define BB    512
#define CC    117
#define EMBD  544
#define SCB   49          // scan blocks: 49*1024 >= 50000

typedef short bf16x8 __attribute__((ext_vector_type(8)));
typedef float f32x4  __attribute__((ext_vector_type(4)));

static __device__ __forceinline__ float lrelu(float x){ return x >= 0.f ? x : 0.2f*x; }
static __device__ __forceinline__ unsigned short f2b(float f){
  unsigned int u = __float_as_uint(f);
  unsigned int r = (u + 0x7fffu + ((u >> 16) & 1u)) >> 16;   // RNE
  return (unsigned short)r;
}
static __device__ __forceinline__ float b2f(unsigned short u){
  return __uint_as_float(((unsigned int)u) << 16);
}

// v[k] = sum_j W[k*256+j]*a[j] for 32 (l,rel,which) combos; one wave per output k
__global__ void vcompute_k(const float* __restrict__ Wsho, const float* __restrict__ Wdho,
                           const float* __restrict__ asho, const float* __restrict__ adho,
                           const float* __restrict__ Wsoh, const float* __restrict__ Wdoh,
                           const float* __restrict__ asoh, const float* __restrict__ adoh,
                           float* __restrict__ vbuf){
  int gid = blockIdx.x*blockDim.x + threadIdx.x;
  int wv = gid >> 6, lane = gid & 63;
  if (wv >= 32*DIM) return;
  int p = wv >> 8, k = wv & 255;
  int which = p & 1, rel = (p>>1)&1, l = p>>2;
  const float* W; const float* a;
  if (rel==0){ W = which? Wdho : Wsho; a = which? adho : asho; }
  else       { W = which? Wdoh : Wsoh; a = which? adoh : asoh; }
  W += (size_t)l*DIM*DIM; a += (size_t)l*DIM;
  const float4* w4 = (const float4*)(W + (size_t)k*DIM);
  const float4* a4 = (const float4*)a;
  float4 wv4 = w4[lane], av4 = a4[lane];
  float s = wv4.x*av4.x + wv4.y*av4.y + wv4.z*av4.z + wv4.w*av4.w;
  for (int off=32; off; off>>=1) s += __shfl_xor(s, off);
  if (lane==0) vbuf[(size_t)p*DIM + k] = s;
}

__global__ void wecompute_k(const float* __restrict__ Weho, const float* __restrict__ aeho,
                            const float* __restrict__ Weoh, const float* __restrict__ aeoh,
                            float* __restrict__ webuf){
  int blk = blockIdx.x;            // l*2 + rel
  int rel = blk & 1, l = blk >> 1;
  const float* We = rel? Weoh : Weho;
  const float* ae = rel? aeoh : aeho;
  int lane = threadIdx.x;          // 64
  const float4* w0 = (const float4*)(We + (size_t)l*2*DIM);
  const float4* w1 = (const float4*)(We + (size_t)l*2*DIM + DIM);
  const float4* a4 = (const float4*)(ae + (size_t)l*DIM);
  float4 av = a4[lane], x0 = w0[lane], x1 = w1[lane];
  float s0 = x0.x*av.x + x0.y*av.y + x0.z*av.z + x0.w*av.w;
  float s1 = x1.x*av.x + x1.y*av.y + x1.z*av.z + x1.w*av.w;
  for (int off=32; off; off>>=1){ s0 += __shfl_xor(s0, off); s1 += __shfl_xor(s1, off); }
  if (lane==0){ webuf[blk*2] = s0; webuf[blk*2+1] = s1; }
}

// 3 histograms in one launch: y=0 dst(ho), y=1 dst(oh), y=2 src(ho)
__global__ void hist3_k(const int* __restrict__ ei_ho, const int* __restrict__ ei_oh,
                        int* __restrict__ cnt_ho, int* __restrict__ cnt_oh,
                        int* __restrict__ cnt_src){
  int e = blockIdx.x*blockDim.x + threadIdx.x;
  if (e >= EDG) return;
  int y = blockIdx.y;
  if (y == 0)      atomicAdd(&cnt_ho[ei_ho[EDG + e]], 1);
  else if (y == 1) atomicAdd(&cnt_oh[ei_oh[EDG + e]], 1);
  else             atomicAdd(&cnt_src[ei_ho[e]], 1);
}

// hierarchical scan over 3 arrays of N=NNODE ints.
// Phase A: per-block sums (grid SCB x 3, 256 thr, 4 elem/thr)
__global__ void scanA_k(const int* __restrict__ c0, const int* __restrict__ c1,
                        const int* __restrict__ c2, int* __restrict__ bsum){
  __shared__ int sh[256];
  int y = blockIdx.y, b = blockIdx.x, t = threadIdx.x;
  const int* cnt = (y==0)? c0 : (y==1)? c1 : c2;
  int idx = b*1024 + t*4;
  int s = 0;
  if (idx + 3 < NNODE){
    int4 v = *(const int4*)(cnt + idx);
    s = v.x + v.y + v.z + v.w;
  } else {
    for (int j=0;j<4;j++) if (idx+j < NNODE) s += cnt[idx+j];
  }
  sh[t] = s; __syncthreads();
  for (int off=128; off; off>>=1){ if (t<off) sh[t] += sh[t+off]; __syncthreads(); }
  if (t==0) bsum[y*SCB + b] = sh[0];
}

// Phase B: scan the 3*SCB block sums (3 threads, serial 49 each) + write rp[N]
__global__ void scanB_k(int* __restrict__ bsum, int* __restrict__ boff,
                        int* __restrict__ rp0, int* __restrict__ rp1, int* __restrict__ rp2){
  int t = threadIdx.x;
  if (t >= 3) return;
  int run = 0;
  for (int i=0;i<SCB;i++){ boff[t*SCB+i] = run; run += bsum[t*SCB+i]; }
  int* rp = (t==0)? rp0 : (t==1)? rp1 : rp2;
  rp[NNODE] = run;
}

// Phase C: in-block exclusive scan + block offset -> rowptr
__global__ void scanC_k(const int* __restrict__ c0, const int* __restrict__ c1,
                        const int* __restrict__ c2, const int* __restrict__ boff,
                        int* __restrict__ rp0, int* __restrict__ rp1, int* __restrict__ rp2){
  __shared__ int sh[256];
  int y = blockIdx.y, b = blockIdx.x, t = threadIdx.x;
  const int* cnt = (y==0)? c0 : (y==1)? c1 : c2;
  int* rp = (y==0)? rp0 : (y==1)? rp1 : rp2;
  int idx = b*1024 + t*4;
  int c[4] = {0,0,0,0};
  if (idx + 3 < NNODE){
    int4 v = *(const int4*)(cnt + idx);
    c[0]=v.x; c[1]=v.y; c[2]=v.z; c[3]=v.w;
  } else {
    for (int j=0;j<4;j++) if (idx+j < NNODE) c[j] = cnt[idx+j];
  }
  int mysum = c[0]+c[1]+c[2]+c[3];
  sh[t] = mysum; __syncthreads();
  for (int off=1; off<256; off<<=1){
    int v = (t>=off) ? sh[t-off] : 0;
    __syncthreads();
    sh[t] += v;
    __syncthreads();
  }
  int base = boff[y*SCB + b] + (sh[t] - mysum);
  int run = 0;
  for (int j=0;j<4;j++){
    if (idx+j < NNODE) rp[idx+j] = base + run;
    run += c[j];
  }
}

// dst-CSR scatter: srcs + permuted edge attrs
__global__ void scatter_k(const int* __restrict__ ei, const float* __restrict__ ea,
                          const int* __restrict__ rowptr, int* __restrict__ cursor,
                          int* __restrict__ srcs, float2* __restrict__ eaperm){
  int e = blockIdx.x*blockDim.x + threadIdx.x;
  if (e >= EDG) return;
  int d = ei[EDG + e];
  int pos = rowptr[d] + atomicAdd(&cursor[d], 1);
  srcs[pos] = ei[e];
  eaperm[pos] = make_float2(ea[2*e], ea[2*e+1]);
}

// src-CSR scatter (ho only): permuted edge attrs for epool
__global__ void scatter_src_k(const int* __restrict__ ei, const float* __restrict__ ea,
                              const int* __restrict__ rowptr, int* __restrict__ cursor,
                              float2* __restrict__ eaperm){
  int e = blockIdx.x*blockDim.x + threadIdx.x;
  if (e >= EDG) return;
  int s = ei[e];
  int pos = rowptr[s] + atomicAdd(&cursor[s], 1);
  eaperm[pos] = make_float2(ea[2*e], ea[2*e+1]);
}

// Wt[rel][l][n][k] = bf16(W[rel][l][k][n])
__global__ void wtconv_k(const float* __restrict__ Who, const float* __restrict__ Woh,
                         unsigned short* __restrict__ Wt){
  int gid = blockIdx.x*blockDim.x + threadIdx.x;   // < 1048576
  int rel = gid >> 19;
  int rem = gid & ((1<<19)-1);
  int l = rem >> 16;
  int idx = rem & 65535;
  int n = idx >> 8, k = idx & 255;
  const float* W = rel ? Woh : Who;
  Wt[gid] = f2b(W[(size_t)l*65536 + (size_t)k*256 + n]);
}

// H[M,256](bf16) = bf16(A[M,256](fp32)) @ B, Bt[n][k](bf16). 128x128 tile, 4 waves.
__global__ __launch_bounds__(256) void gemmb_k(const float* __restrict__ A,
                                               const unsigned short* __restrict__ Bt,
                                               unsigned short* __restrict__ H, int M){
  __shared__ __align__(16) unsigned short As[4096];
  __shared__ __align__(16) unsigned short Bs[4096];
  int tid = threadIdx.x;
  int col0 = blockIdx.x * 128;
  int row0 = blockIdx.y * 128;
  int w = tid >> 6, lane = tid & 63;
  int q = lane >> 4, ml = lane & 15;
  f32x4 acc[2][8];
  #pragma unroll
  for (int i=0;i<2;i++)
    #pragma unroll
    for (int j=0;j<8;j++) acc[i][j] = (f32x4){0.f,0.f,0.f,0.f};
  int srow = tid >> 2;    // 0..63
  int sq   = tid & 3;
  for (int k0 = 0; k0 < 256; k0 += 32){
    #pragma unroll
    for (int p = 0; p < 2; ++p){
      int row = p*64 + srow;
      int gr = row0 + row;
      ushort4 a8[2] = {make_ushort4(0,0,0,0), make_ushort4(0,0,0,0)};
      if (gr < M){
        const float* ap = A + (size_t)gr*256 + k0 + sq*8;
        float4 f0 = *(const float4*)ap;
        float4 f1 = *(const float4*)(ap + 4);
        a8[0] = make_ushort4(f2b(f0.x), f2b(f0.y), f2b(f0.z), f2b(f0.w));
        a8[1] = make_ushort4(f2b(f1.x), f2b(f1.y), f2b(f1.z), f2b(f1.w));
      }
      *(ushort4*)&As[((((row>>4)*4) + sq)*16 + (row&15))*8 + 0] = a8[0];
      *(ushort4*)&As[((((row>>4)*4) + sq)*16 + (row&15))*8 + 4] = a8[1];
      int gc = col0 + row;
      uint4 bv = *(const uint4*)(Bt + (size_t)gc*256 + k0 + sq*8);
      *(uint4*)&Bs[((((row>>4)*4) + sq)*16 + (row&15))*8] = bv;
    }
    __syncthreads();
    bf16x8 a0 = *(const bf16x8*)&As[(((2*w+0)*4 + q)*16 + ml)*8];
    bf16x8 a1 = *(const bf16x8*)&As[(((2*w+1)*4 + q)*16 + ml)*8];
    #pragma unroll
    for (int nf = 0; nf < 8; ++nf){
      bf16x8 b = *(const bf16x8*)&Bs[((nf*4 + q)*16 + ml)*8];
      acc[0][nf] = __builtin_amdgcn_mfma_f32_16x16x32_bf16(a0, b, acc[0][nf], 0,0,0);
      acc[1][nf] = __builtin_amdgcn_mfma_f32_16x16x32_bf16(a1, b, acc[1][nf], 0,0,0);
    }
    __syncthreads();
  }
  #pragma unroll
  for (int mf = 0; mf < 2; ++mf){
    #pragma unroll
    for (int r = 0; r < 4; ++r){
      int gr = row0 + 32*w + 16*mf + q*4 + r;
      if (gr < M){
        #pragma unroll
        for (int nf = 0; nf < 8; ++nf)
          H[(size_t)gr*256 + col0 + nf*16 + ml] = f2b(acc[mf][nf][r]);
      }
    }
  }
}

// o1 = X@v1, o2 = X@v2 (one wave per row), fp32 — layer 0 only
__global__ void dgemv_k(const float* __restrict__ X, const float* __restrict__ v1,
                        const float* __restrict__ v2, float* __restrict__ o1,
                        float* __restrict__ o2){
  int gid = blockIdx.x*blockDim.x + threadIdx.x;
  int w = gid >> 6, lane = gid & 63;
  if (w >= NNODE) return;
  const float4* x4 = (const float4*)(X + (size_t)w*DIM);
  float4 xv = x4[lane];
  float4 a = ((const float4*)v1)[lane];
  float4 b = ((const float4*)v2)[lane];
  float s1 = xv.x*a.x + xv.y*a.y + xv.z*a.z + xv.w*a.w;
  float s2 = xv.x*b.x + xv.y*b.y + xv.z*b.z + xv.w*b.w;
  for (int off=32; off; off>>=1){ s1 += __shfl_xor(s1, off); s2 += __shfl_xor(s2, off); }
  if (lane==0){ o1[w] = s1; o2[w] = s2; }
}

// one wave per dst node: segment softmax + weighted gather of bf16 h_src rows.
// Fast path deg<=64: lane-per-edge, weights broadcast via shfl into gather loop.
// Epilogue: optional next-layer a_s/a_d dots (replaces dgemv).
__global__ void attn_k(const int* __restrict__ rowptr, const int* __restrict__ srcs,
                       const float2* __restrict__ eaperm, const float* __restrict__ a_s,
                       const float* __restrict__ a_d,
                       const float* __restrict__ wep, const unsigned short* __restrict__ hs,
                       const float* __restrict__ bias, const float* __restrict__ xprev,
                       float* __restrict__ xnext,
                       const float* __restrict__ vsn, const float* __restrict__ vdn,
                       float* __restrict__ asn, float* __restrict__ adn,
                       int hasRes, int doNext){
  int gid = blockIdx.x*blockDim.x + threadIdx.x;
  int w = gid >> 6, lane = gid & 63;
  if (w >= NNODE) return;
  int st = rowptr[w], en = rowptr[w+1];
  int deg = en - st;
  float w0 = wep[0], w1 = wep[1];
  float adv = a_d[w];
  float ax=0.f, ay=0.f, az=0.f, aw=0.f;
  const ushort4* h4 = (const ushort4*)hs;
  if (deg > 0 && deg <= 64){
    int sreg = 0; float lg = -INFINITY;
    if (lane < deg){
      sreg = srcs[st + lane];
      float2 ev = eaperm[st + lane];
      lg = lrelu(a_s[sreg] + adv + ev.x*w0 + ev.y*w1);
    }
    float mx = lg;
    for (int off=32; off; off>>=1) mx = fmaxf(mx, __shfl_xor(mx, off));
    float ex = (lane < deg) ? expf(lg - mx) : 0.f;
    float sm = ex;
    for (int off=32; off; off>>=1) sm += __shfl_xor(sm, off);
    float wgt = ex / sm;
    for (int i=0;i<deg;i++){
      float wi = __shfl(wgt, i);
      int   si = __shfl(sreg, i);
      ushort4 hv = h4[(size_t)si*64 + lane];
      ax += wi*b2f(hv.x); ay += wi*b2f(hv.y); az += wi*b2f(hv.z); aw += wi*b2f(hv.w);
    }
  } else if (deg > 64){
    float mx = -INFINITY;
    for (int p = st + lane; p < en; p += 64){
      float2 ev = eaperm[p];
      float lg = lrelu(a_s[srcs[p]] + adv + ev.x*w0 + ev.y*w1);
      mx = fmaxf(mx, lg);
    }
    for (int off=32; off; off>>=1) mx = fmaxf(mx, __shfl_xor(mx, off));
    float sm = 0.f;
    for (int p = st + lane; p < en; p += 64){
      float2 ev = eaperm[p];
      float lg = lrelu(a_s[srcs[p]] + adv + ev.x*w0 + ev.y*w1);
      sm += expf(lg - mx);
    }
    for (int off=32; off; off>>=1) sm += __shfl_xor(sm, off);
    float inv = 1.f/sm;
    for (int p = st; p < en; ++p){
      float2 ev = eaperm[p];
      int s = srcs[p];
      float lg = lrelu(a_s[s] + adv + ev.x*w0 + ev.y*w1);
      float wgt = expf(lg - mx) * inv;
      ushort4 hv = h4[(size_t)s*64 + lane];
      ax += wgt*b2f(hv.x); ay += wgt*b2f(hv.y); az += wgt*b2f(hv.z); aw += wgt*b2f(hv.w);
    }
  }
  float4 bv = ((const float4*)bias)[lane];
  float4 o;
  o.x = fmaxf(ax + bv.x, 0.f);
  o.y = fmaxf(ay + bv.y, 0.f);
  o.z = fmaxf(az + bv.z, 0.f);
  o.w = fmaxf(aw + bv.w, 0.f);
  if (hasRes){
    float4 r = ((const float4*)xprev)[(size_t)w*64 + lane];
    o.x += r.x; o.y += r.y; o.z += r.z; o.w += r.w;
  }
  ((float4*)xnext)[(size_t)w*64 + lane] = o;
  if (doNext){
    float4 a = ((const float4*)vsn)[lane];
    float4 b = ((const float4*)vdn)[lane];
    float s1 = o.x*a.x + o.y*a.y + o.z*a.z + o.w*a.w;
    float s2 = o.x*b.x + o.y*b.y + o.z*b.z + o.w*b.w;
    for (int off=32; off; off>>=1){ s1 += __shfl_xor(s1, off); s2 += __shfl_xor(s2, off); }
    if (lane==0){ asn[w] = s1; adn[w] = s2; }
  }
}

__device__ __forceinline__ int lowerb(const int* a, int n, int v){
  int lo=0, hi=n;
  while (lo < hi){ int m = (lo+hi)>>1; if (a[m] < v) lo = m+1; else hi = m; }
  return lo;
}

__global__ void pool_k(const float* __restrict__ x, const int* __restrict__ batch,
                       float* __restrict__ out){
  int b = blockIdx.x, t = threadIdx.x; // 256
  int st = lowerb(batch, NNODE, b), en = lowerb(batch, NNODE, b+1);
  float s = 0.f;
  for (int i=st;i<en;i++) s += x[(size_t)i*DIM + t];
  out[(size_t)b*DIM + t] = s / fmaxf((float)(en - st), 1.f);
}

// fused edge-MLP pool: hbatch sorted + src-CSR => batch b's edges contiguous.
__global__ void epool_k(const int* __restrict__ rp_src, const int* __restrict__ hbatch,
                        const float2* __restrict__ eaperm, const float* __restrict__ Wem,
                        const float* __restrict__ bem, float* __restrict__ epool){
  __shared__ float ps[8][33];
  int b = blockIdx.x, t = threadIdx.x; // 256
  int j = t & 31, g = t >> 5;
  int nst = lowerb(hbatch, NNODE, b), nen = lowerb(hbatch, NNODE, b+1);
  int est = rp_src[nst], een = rp_src[nen];
  float w0 = Wem[j], w1 = Wem[32+j], bb = bem[j];
  float s = 0.f;
  for (int p = est + g; p < een; p += 8){
    float2 e = eaperm[p];
    s += fmaxf(e.x*w0 + e.y*w1 + bb, 0.f);
  }
  ps[g][j] = s; __syncthreads();
  if (g == 0){
    float tot = 0.f;
    #pragma unroll
    for (int gg=0; gg<8; gg++) tot += ps[gg][j];
    epool[(size_t)b*32 + j] = tot / fmaxf((float)(een - est), 1.f);
  }
}

__global__ void head_k(const float* __restrict__ hpool, const float* __restrict__ opool,
                       const float* __restrict__ epool,
                       const float* __restrict__ Wp1, const float* __restrict__ bp1,
                       const float* __restrict__ Wp2, const float* __restrict__ bp2,
                       float* __restrict__ out){
  __shared__ float emb[EMBD];
  __shared__ float red[256];
  int b = blockIdx.x, t = threadIdx.x; // 256
  emb[t] = hpool[(size_t)b*DIM + t];
  emb[DIM + t] = opool[(size_t)b*DIM + t];
  if (t < 32) emb[2*DIM + t] = epool[(size_t)b*32 + t];
  __syncthreads();
  for (int h = 0; h < 2; ++h){
    const float* Wp = h? Wp2 : Wp1;
    const float* bp = h? bp2 : bp1;
    float logit = -INFINITY;
    if (t < CC){
      float s = bp[t];
      for (int k=0;k<EMBD;k++) s += emb[k]*Wp[(size_t)k*CC + t];
      logit = s;
    }
    red[t] = logit; __syncthreads();
    for (int off=128; off; off>>=1){ if (t<off) red[t] = fmaxf(red[t], red[t+off]); __syncthreads(); }
    float mx = red[0]; __syncthreads();
    float ex = (t < CC) ? expf(logit - mx) : 0.f;
    red[t] = ex; __syncthreads();
    for (int off=128; off; off>>=1){ if (t<off) red[t] += red[t+off]; __syncthreads(); }
    float sm = red[0]; __syncthreads();
    if (t < CC) out[((size_t)b*2 + h)*CC + t] = ex / sm;
  }
}

extern "C" void kernel_launch(void* const* d_in, const int* in_sizes, int n_in,
                              void* d_out, int out_size, void* d_ws, size_t ws_size,
                              hipStream_t stream) {
  (void)in_sizes; (void)n_in; (void)out_size; (void)ws_size;
  const float* xh_in   = (const float*)d_in[0];
  const float* xo_in   = (const float*)d_in[1];
  const int*   ei_ho   = (const int*)d_in[2];
  const int*   ei_oh   = (const int*)d_in[3];
  const float* ea_ho   = (const float*)d_in[4];
  const float* ea_oh   = (const float*)d_in[5];
  const int*   hbatch  = (const int*)d_in[6];
  const int*   obatch  = (const int*)d_in[7];
  const float* Wsrc_ho = (const float*)d_in[8];
  const float* Wdst_ho = (const float*)d_in[9];
  const float* asrc_ho = (const float*)d_in[10];
  const float* adst_ho = (const float*)d_in[11];
  const float* Wedge_ho= (const float*)d_in[12];
  const float* aedge_ho= (const float*)d_in[13];
  const float* bias_ho = (const float*)d_in[14];
  const float* Wsrc_oh = (const float*)d_in[15];
  const float* Wdst_oh = (const float*)d_in[16];
  const float* asrc_oh = (const float*)d_in[17];
  const float* adst_oh = (const float*)d_in[18];
  const float* Wedge_oh= (const float*)d_in[19];
  const float* aedge_oh= (const float*)d_in[20];
  const float* bias_oh = (const float*)d_in[21];
  const float* W_emlp  = (const float*)d_in[22];
  const float* b_emlp  = (const float*)d_in[23];
  const float* W_p1    = (const float*)d_in[24];
  const float* b_p1    = (const float*)d_in[25];
  const float* W_p2    = (const float*)d_in[26];
  const float* b_p2    = (const float*)d_in[27];
  float* out = (float*)d_out;

  size_t ND = (size_t)NNODE*DIM;
  float* f = (float*)d_ws;
  float* xh0 = f;
  float* xh1 = f + ND;
  float* xo0 = f + 2*ND;
  float* xo1 = f + 3*ND;
  float* aset0 = f + 4*ND;                 // [asho adho asoh adoh] set 0
  float* aset1 = aset0 + 4*NNODE;          // set 1
  float* vbuf  = aset1 + 4*NNODE;          // 32*256
  float* webuf = vbuf + 32*DIM;            // 32
  float* hpool = webuf + 32;               // BB*DIM
  float* opool = hpool + (size_t)BB*DIM;
  float* epool = opool + (size_t)BB*DIM;   // BB*32
  float2* eap_ho  = (float2*)(epool + (size_t)BB*32);   // E float2
  float2* eap_oh  = eap_ho + EDG;
  float2* eap_src = eap_oh + EDG;
  unsigned short* hSb = (unsigned short*)(eap_src + EDG);  // ND bf16
  unsigned short* Wtb = hSb + ND;          // 2*8*65536 bf16
  int* cnt_ho  = (int*)(Wtb + (size_t)2*LAY*DIM*DIM);
  int* cnt_oh  = cnt_ho + NNODE;
  int* cnt_src = cnt_oh + NNODE;
  int* rp_ho   = cnt_src + NNODE;
  int* rp_oh   = rp_ho + NNODE + 1;
  int* rp_src  = rp_oh + NNODE + 1;
  int* srcs_ho = rp_src + NNODE + 1;
  int* srcs_oh = srcs_ho + EDG;
  int* bsum    = srcs_oh + EDG;            // 3*SCB
  int* boff    = bsum + 3*SCB;             // 3*SCB

  hipMemsetAsync(cnt_ho, 0, sizeof(int)*3*NNODE, stream);
  vcompute_k<<<2048, 256, 0, stream>>>(Wsrc_ho, Wdst_ho, asrc_ho, adst_ho,
                                       Wsrc_oh, Wdst_oh, asrc_oh, adst_oh, vbuf);
  wecompute_k<<<16, 64, 0, stream>>>(Wedge_ho, aedge_ho, Wedge_oh, aedge_oh, webuf);
  wtconv_k<<<4096, 256, 0, stream>>>(Wsrc_ho, Wsrc_oh, Wtb);
  hist3_k<<<dim3(1954,3), 256, 0, stream>>>(ei_ho, ei_oh, cnt_ho, cnt_oh, cnt_src);
  scanA_k<<<dim3(SCB,3), 256, 0, stream>>>(cnt_ho, cnt_oh, cnt_src, bsum);
  scanB_k<<<1, 64, 0, stream>>>(bsum, boff, rp_ho, rp_oh, rp_src);
  scanC_k<<<dim3(SCB,3), 256, 0, stream>>>(cnt_ho, cnt_oh, cnt_src, boff, rp_ho, rp_oh, rp_src);
  hipMemsetAsync(cnt_ho, 0, sizeof(int)*3*NNODE, stream);            // reuse as cursors
  scatter_k<<<1954, 256, 0, stream>>>(ei_ho, ea_ho, rp_ho, cnt_ho, srcs_ho, eap_ho);
  scatter_k<<<1954, 256, 0, stream>>>(ei_oh, ea_oh, rp_oh, cnt_oh, srcs_oh, eap_oh);
  scatter_src_k<<<1954, 256, 0, stream>>>(ei_ho, ea_ho, rp_src, cnt_src, eap_src);

  // layer-0 a_s/a_d from fp32 inputs
  dgemv_k<<<12500, 256, 0, stream>>>(xh_in, vbuf + (size_t)0*DIM, vbuf + (size_t)3*DIM,
                                     aset0 + 0*NNODE, aset0 + 3*NNODE);
  dgemv_k<<<12500, 256, 0, stream>>>(xo_in, vbuf + (size_t)2*DIM, vbuf + (size_t)1*DIM,
                                     aset0 + 2*NNODE, aset0 + 1*NNODE);

  const float* xh = xh_in;
  const float* xo = xo_in;
  float* xh_bufs[2] = {xh0, xh1};
  float* xo_bufs[2] = {xo0, xo1};
  float* asets[2] = {aset0, aset1};
  for (int l = 0; l < LAY; ++l){
    float* xo_n = xo_bufs[l & 1];
    float* xh_n = xh_bufs[l & 1];
    float* cur = asets[l & 1];
    float* nxt = asets[(l & 1) ^ 1];
    int doNext = (l < LAY-1);
    int ln = doNext ? (l+1) : l;   // valid vbuf index even when unused
    // relation ho: src=human, dst=object -> new xo; epilogue: asoh,adho for l+1
    gemmb_k<<<dim3(2, 391), 256, 0, stream>>>(xh, Wtb + (size_t)l*DIM*DIM, hSb, NNODE);
    attn_k<<<12500, 256, 0, stream>>>(rp_ho, srcs_ho, eap_ho,
                                      cur + 0*NNODE, cur + 1*NNODE,
                                      webuf + (size_t)(l*2+0)*2, hSb,
                                      bias_ho + (size_t)l*DIM, xo, xo_n,
                                      vbuf + (size_t)(ln*4+2)*DIM, vbuf + (size_t)(ln*4+1)*DIM,
                                      nxt + 2*NNODE, nxt + 1*NNODE, l > 0, doNext);
    // relation oh: src=object, dst=human -> new xh; epilogue: asho,adoh for l+1
    gemmb_k<<<dim3(2, 391), 256, 0, stream>>>(xo, Wtb + (size_t)(LAY + l)*DIM*DIM, hSb, NNODE);
    attn_k<<<12500, 256, 0, stream>>>(rp_oh, srcs_oh, eap_oh,
                                      cur + 2*NNODE, cur + 3*NNODE,
                                      webuf + (size_t)(l*2+1)*2, hSb,
                                      bias_oh + (size_t)l*DIM, xh, xh_n,
                                      vbuf + (size_t)(ln*4+0)*DIM, vbuf + (size_t)(ln*4+3)*DIM,
                                      nxt + 0*NNODE, nxt + 3*NNODE, l > 0, doNext);
    xh = xh_n; xo = xo_n;
  }

  pool_k<<<BB, 256, 0, stream>>>(xh, hbatch, hpool);
  pool_k<<<BB, 256, 0, stream>>>(xo, obatch, opool);
  epool_k<<<BB, 256, 0, stream>>>(rp_src, hbatch, eap_src, W_emlp, b_emlp, epool);
  head_k<<<BB, 256, 0, stream>>>(hpool, opool, epool, W_p1, b_p1, W_p2, b_p2, out);
}

// Round 6
// 1741.718 us; speedup vs baseline: 2.9518x; 1.2019x over previous
//
#include <hip/hip_runtime.h>
#include <math.h>

// HELPv3: 8-layer bipartite GAT + pooling + 2 softmax heads.
// R6: (1) bf16 x-stream everywhere (residual/pool/gemm) - halves x traffic
//     (2) 4-way unrolled gather in attn fast path (MLP on latency-bound gather)
// Carried: bf16 MFMA GEMM, hierarchical scan, fused epilogue GEMVs, CSR epool.

#define NNODE 50000
#define EDG   500000
#define DIM   256
#define LAY   8
#define BB    512
#define CC    117
#define EMBD  544
#define SCB   49          // scan blocks: 49*1024 >= 50000

typedef short bf16x8 __attribute__((ext_vector_type(8)));
typedef float f32x4  __attribute__((ext_vector_type(4)));

static __device__ __forceinline__ float lrelu(float x){ return x >= 0.f ? x : 0.2f*x; }
static __device__ __forceinline__ unsigned short f2b(float f){
  unsigned int u = __float_as_uint(f);
  unsigned int r = (u + 0x7fffu + ((u >> 16) & 1u)) >> 16;   // RNE
  return (unsigned short)r;
}
static __device__ __forceinline__ float b2f(unsigned short u){
  return __uint_as_float(((unsigned int)u) << 16);
}

// v[k] = sum_j W[k*256+j]*a[j] for 32 (l,rel,which) combos; one wave per output k
__global__ void vcompute_k(const float* __restrict__ Wsho, const float* __restrict__ Wdho,
                           const float* __restrict__ asho, const float* __restrict__ adho,
                           const float* __restrict__ Wsoh, const float* __restrict__ Wdoh,
                           const float* __restrict__ asoh, const float* __restrict__ adoh,
                           float* __restrict__ vbuf){
  int gid = blockIdx.x*blockDim.x + threadIdx.x;
  int wv = gid >> 6, lane = gid & 63;
  if (wv >= 32*DIM) return;
  int p = wv >> 8, k = wv & 255;
  int which = p & 1, rel = (p>>1)&1, l = p>>2;
  const float* W; const float* a;
  if (rel==0){ W = which? Wdho : Wsho; a = which? adho : asho; }
  else       { W = which? Wdoh : Wsoh; a = which? adoh : asoh; }
  W += (size_t)l*DIM*DIM; a += (size_t)l*DIM;
  const float4* w4 = (const float4*)(W + (size_t)k*DIM);
  const float4* a4 = (const float4*)a;
  float4 wv4 = w4[lane], av4 = a4[lane];
  float s = wv4.x*av4.x + wv4.y*av4.y + wv4.z*av4.z + wv4.w*av4.w;
  for (int off=32; off; off>>=1) s += __shfl_xor(s, off);
  if (lane==0) vbuf[(size_t)p*DIM + k] = s;
}

__global__ void wecompute_k(const float* __restrict__ Weho, const float* __restrict__ aeho,
                            const float* __restrict__ Weoh, const float* __restrict__ aeoh,
                            float* __restrict__ webuf){
  int blk = blockIdx.x;            // l*2 + rel
  int rel = blk & 1, l = blk >> 1;
  const float* We = rel? Weoh : Weho;
  const float* ae = rel? aeoh : aeho;
  int lane = threadIdx.x;          // 64
  const float4* w0 = (const float4*)(We + (size_t)l*2*DIM);
  const float4* w1 = (const float4*)(We + (size_t)l*2*DIM + DIM);
  const float4* a4 = (const float4*)(ae + (size_t)l*DIM);
  float4 av = a4[lane], x0 = w0[lane], x1 = w1[lane];
  float s0 = x0.x*av.x + x0.y*av.y + x0.z*av.z + x0.w*av.w;
  float s1 = x1.x*av.x + x1.y*av.y + x1.z*av.z + x1.w*av.w;
  for (int off=32; off; off>>=1){ s0 += __shfl_xor(s0, off); s1 += __shfl_xor(s1, off); }
  if (lane==0){ webuf[blk*2] = s0; webuf[blk*2+1] = s1; }
}

// 3 histograms in one launch: y=0 dst(ho), y=1 dst(oh), y=2 src(ho)
__global__ void hist3_k(const int* __restrict__ ei_ho, const int* __restrict__ ei_oh,
                        int* __restrict__ cnt_ho, int* __restrict__ cnt_oh,
                        int* __restrict__ cnt_src){
  int e = blockIdx.x*blockDim.x + threadIdx.x;
  if (e >= EDG) return;
  int y = blockIdx.y;
  if (y == 0)      atomicAdd(&cnt_ho[ei_ho[EDG + e]], 1);
  else if (y == 1) atomicAdd(&cnt_oh[ei_oh[EDG + e]], 1);
  else             atomicAdd(&cnt_src[ei_ho[e]], 1);
}

// hierarchical scan over 3 arrays of N=NNODE ints.
__global__ void scanA_k(const int* __restrict__ c0, const int* __restrict__ c1,
                        const int* __restrict__ c2, int* __restrict__ bsum){
  __shared__ int sh[256];
  int y = blockIdx.y, b = blockIdx.x, t = threadIdx.x;
  const int* cnt = (y==0)? c0 : (y==1)? c1 : c2;
  int idx = b*1024 + t*4;
  int s = 0;
  if (idx + 3 < NNODE){
    int4 v = *(const int4*)(cnt + idx);
    s = v.x + v.y + v.z + v.w;
  } else {
    for (int j=0;j<4;j++) if (idx+j < NNODE) s += cnt[idx+j];
  }
  sh[t] = s; __syncthreads();
  for (int off=128; off; off>>=1){ if (t<off) sh[t] += sh[t+off]; __syncthreads(); }
  if (t==0) bsum[y*SCB + b] = sh[0];
}

__global__ void scanB_k(int* __restrict__ bsum, int* __restrict__ boff,
                        int* __restrict__ rp0, int* __restrict__ rp1, int* __restrict__ rp2){
  int t = threadIdx.x;
  if (t >= 3) return;
  int run = 0;
  for (int i=0;i<SCB;i++){ boff[t*SCB+i] = run; run += bsum[t*SCB+i]; }
  int* rp = (t==0)? rp0 : (t==1)? rp1 : rp2;
  rp[NNODE] = run;
}

__global__ void scanC_k(const int* __restrict__ c0, const int* __restrict__ c1,
                        const int* __restrict__ c2, const int* __restrict__ boff,
                        int* __restrict__ rp0, int* __restrict__ rp1, int* __restrict__ rp2){
  __shared__ int sh[256];
  int y = blockIdx.y, b = blockIdx.x, t = threadIdx.x;
  const int* cnt = (y==0)? c0 : (y==1)? c1 : c2;
  int* rp = (y==0)? rp0 : (y==1)? rp1 : rp2;
  int idx = b*1024 + t*4;
  int c[4] = {0,0,0,0};
  if (idx + 3 < NNODE){
    int4 v = *(const int4*)(cnt + idx);
    c[0]=v.x; c[1]=v.y; c[2]=v.z; c[3]=v.w;
  } else {
    for (int j=0;j<4;j++) if (idx+j < NNODE) c[j] = cnt[idx+j];
  }
  int mysum = c[0]+c[1]+c[2]+c[3];
  sh[t] = mysum; __syncthreads();
  for (int off=1; off<256; off<<=1){
    int v = (t>=off) ? sh[t-off] : 0;
    __syncthreads();
    sh[t] += v;
    __syncthreads();
  }
  int base = boff[y*SCB + b] + (sh[t] - mysum);
  int run = 0;
  for (int j=0;j<4;j++){
    if (idx+j < NNODE) rp[idx+j] = base + run;
    run += c[j];
  }
}

// dst-CSR scatter: srcs + permuted edge attrs
__global__ void scatter_k(const int* __restrict__ ei, const float* __restrict__ ea,
                          const int* __restrict__ rowptr, int* __restrict__ cursor,
                          int* __restrict__ srcs, float2* __restrict__ eaperm){
  int e = blockIdx.x*blockDim.x + threadIdx.x;
  if (e >= EDG) return;
  int d = ei[EDG + e];
  int pos = rowptr[d] + atomicAdd(&cursor[d], 1);
  srcs[pos] = ei[e];
  eaperm[pos] = make_float2(ea[2*e], ea[2*e+1]);
}

// src-CSR scatter (ho only): permuted edge attrs for epool
__global__ void scatter_src_k(const int* __restrict__ ei, const float* __restrict__ ea,
                              const int* __restrict__ rowptr, int* __restrict__ cursor,
                              float2* __restrict__ eaperm){
  int e = blockIdx.x*blockDim.x + threadIdx.x;
  if (e >= EDG) return;
  int s = ei[e];
  int pos = rowptr[s] + atomicAdd(&cursor[s], 1);
  eaperm[pos] = make_float2(ea[2*e], ea[2*e+1]);
}

// fp32 -> bf16 bulk convert (n4 = elements/4)
__global__ void xconv_k(const float* __restrict__ in, unsigned short* __restrict__ out, int n4){
  int i = blockIdx.x*blockDim.x + threadIdx.x;
  if (i >= n4) return;
  float4 v = ((const float4*)in)[i];
  ushort4 o; o.x=f2b(v.x); o.y=f2b(v.y); o.z=f2b(v.z); o.w=f2b(v.w);
  ((ushort4*)out)[i] = o;
}

// Wt[rel][l][n][k] = bf16(W[rel][l][k][n])
__global__ void wtconv_k(const float* __restrict__ Who, const float* __restrict__ Woh,
                         unsigned short* __restrict__ Wt){
  int gid = blockIdx.x*blockDim.x + threadIdx.x;   // < 1048576
  int rel = gid >> 19;
  int rem = gid & ((1<<19)-1);
  int l = rem >> 16;
  int idx = rem & 65535;
  int n = idx >> 8, k = idx & 255;
  const float* W = rel ? Woh : Who;
  Wt[gid] = f2b(W[(size_t)l*65536 + (size_t)k*256 + n]);
}

// H[M,256](bf16) = A[M,256](bf16) @ B, Bt[n][k](bf16). 128x128 tile, 4 waves.
__global__ __launch_bounds__(256) void gemmb_k(const unsigned short* __restrict__ A,
                                               const unsigned short* __restrict__ Bt,
                                               unsigned short* __restrict__ H, int M){
  __shared__ __align__(16) unsigned short As[4096];
  __shared__ __align__(16) unsigned short Bs[4096];
  int tid = threadIdx.x;
  int col0 = blockIdx.x * 128;
  int row0 = blockIdx.y * 128;
  int w = tid >> 6, lane = tid & 63;
  int q = lane >> 4, ml = lane & 15;
  f32x4 acc[2][8];
  #pragma unroll
  for (int i=0;i<2;i++)
    #pragma unroll
    for (int j=0;j<8;j++) acc[i][j] = (f32x4){0.f,0.f,0.f,0.f};
  int srow = tid >> 2;    // 0..63
  int sq   = tid & 3;
  for (int k0 = 0; k0 < 256; k0 += 32){
    #pragma unroll
    for (int p = 0; p < 2; ++p){
      int row = p*64 + srow;
      int gr = row0 + row;
      uint4 av = make_uint4(0,0,0,0);
      if (gr < M) av = *(const uint4*)(A + (size_t)gr*256 + k0 + sq*8);
      *(uint4*)&As[((((row>>4)*4) + sq)*16 + (row&15))*8] = av;
      int gc = col0 + row;
      uint4 bv = *(const uint4*)(Bt + (size_t)gc*256 + k0 + sq*8);
      *(uint4*)&Bs[((((row>>4)*4) + sq)*16 + (row&15))*8] = bv;
    }
    __syncthreads();
    bf16x8 a0 = *(const bf16x8*)&As[(((2*w+0)*4 + q)*16 + ml)*8];
    bf16x8 a1 = *(const bf16x8*)&As[(((2*w+1)*4 + q)*16 + ml)*8];
    #pragma unroll
    for (int nf = 0; nf < 8; ++nf){
      bf16x8 b = *(const bf16x8*)&Bs[((nf*4 + q)*16 + ml)*8];
      acc[0][nf] = __builtin_amdgcn_mfma_f32_16x16x32_bf16(a0, b, acc[0][nf], 0,0,0);
      acc[1][nf] = __builtin_amdgcn_mfma_f32_16x16x32_bf16(a1, b, acc[1][nf], 0,0,0);
    }
    __syncthreads();
  }
  #pragma unroll
  for (int mf = 0; mf < 2; ++mf){
    #pragma unroll
    for (int r = 0; r < 4; ++r){
      int gr = row0 + 32*w + 16*mf + q*4 + r;
      if (gr < M){
        #pragma unroll
        for (int nf = 0; nf < 8; ++nf)
          H[(size_t)gr*256 + col0 + nf*16 + ml] = f2b(acc[mf][nf][r]);
      }
    }
  }
}

// o1 = X@v1, o2 = X@v2 (one wave per row), fp32 — layer 0 only
__global__ void dgemv_k(const float* __restrict__ X, const float* __restrict__ v1,
                        const float* __restrict__ v2, float* __restrict__ o1,
                        float* __restrict__ o2){
  int gid = blockIdx.x*blockDim.x + threadIdx.x;
  int w = gid >> 6, lane = gid & 63;
  if (w >= NNODE) return;
  const float4* x4 = (const float4*)(X + (size_t)w*DIM);
  float4 xv = x4[lane];
  float4 a = ((const float4*)v1)[lane];
  float4 b = ((const float4*)v2)[lane];
  float s1 = xv.x*a.x + xv.y*a.y + xv.z*a.z + xv.w*a.w;
  float s2 = xv.x*b.x + xv.y*b.y + xv.z*b.z + xv.w*b.w;
  for (int off=32; off; off>>=1){ s1 += __shfl_xor(s1, off); s2 += __shfl_xor(s2, off); }
  if (lane==0){ o1[w] = s1; o2[w] = s2; }
}

// one wave per dst node: segment softmax + weighted gather of bf16 h_src rows.
// Fast path deg<=64: lane-per-edge logits, 4-way unrolled gather (MLP).
// x stream is bf16 (xprev read, xnext write). Epilogue: next-layer a_s/a_d dots.
__global__ void attn_k(const int* __restrict__ rowptr, const int* __restrict__ srcs,
                       const float2* __restrict__ eaperm, const float* __restrict__ a_s,
                       const float* __restrict__ a_d,
                       const float* __restrict__ wep, const unsigned short* __restrict__ hs,
                       const float* __restrict__ bias, const unsigned short* __restrict__ xprev,
                       unsigned short* __restrict__ xnext,
                       const float* __restrict__ vsn, const float* __restrict__ vdn,
                       float* __restrict__ asn, float* __restrict__ adn,
                       int hasRes, int doNext){
  int gid = blockIdx.x*blockDim.x + threadIdx.x;
  int w = gid >> 6, lane = gid & 63;
  if (w >= NNODE) return;
  int st = rowptr[w], en = rowptr[w+1];
  int deg = en - st;
  float w0 = wep[0], w1 = wep[1];
  float adv = a_d[w];
  float ax=0.f, ay=0.f, az=0.f, aw=0.f;
  const ushort4* h4 = (const ushort4*)hs;
  if (deg > 0 && deg <= 64){
    int sreg = 0; float lg = -INFINITY;
    if (lane < deg){
      sreg = srcs[st + lane];
      float2 ev = eaperm[st + lane];
      lg = lrelu(a_s[sreg] + adv + ev.x*w0 + ev.y*w1);
    }
    float mx = lg;
    for (int off=32; off; off>>=1) mx = fmaxf(mx, __shfl_xor(mx, off));
    float ex = (lane < deg) ? expf(lg - mx) : 0.f;
    float sm = ex;
    for (int off=32; off; off>>=1) sm += __shfl_xor(sm, off);
    float wgt = ex / sm;
    int i = 0;
    for (; i + 3 < deg; i += 4){
      float wi0 = __shfl(wgt, i),   wi1 = __shfl(wgt, i+1);
      float wi2 = __shfl(wgt, i+2), wi3 = __shfl(wgt, i+3);
      int   si0 = __shfl(sreg, i),   si1 = __shfl(sreg, i+1);
      int   si2 = __shfl(sreg, i+2), si3 = __shfl(sreg, i+3);
      ushort4 h0 = h4[(size_t)si0*64 + lane];
      ushort4 h1 = h4[(size_t)si1*64 + lane];
      ushort4 h2 = h4[(size_t)si2*64 + lane];
      ushort4 h3 = h4[(size_t)si3*64 + lane];
      ax += wi0*b2f(h0.x) + wi1*b2f(h1.x) + wi2*b2f(h2.x) + wi3*b2f(h3.x);
      ay += wi0*b2f(h0.y) + wi1*b2f(h1.y) + wi2*b2f(h2.y) + wi3*b2f(h3.y);
      az += wi0*b2f(h0.z) + wi1*b2f(h1.z) + wi2*b2f(h2.z) + wi3*b2f(h3.z);
      aw += wi0*b2f(h0.w) + wi1*b2f(h1.w) + wi2*b2f(h2.w) + wi3*b2f(h3.w);
    }
    for (; i < deg; ++i){
      float wi = __shfl(wgt, i);
      int   si = __shfl(sreg, i);
      ushort4 hv = h4[(size_t)si*64 + lane];
      ax += wi*b2f(hv.x); ay += wi*b2f(hv.y); az += wi*b2f(hv.z); aw += wi*b2f(hv.w);
    }
  } else if (deg > 64){
    float mx = -INFINITY;
    for (int p = st + lane; p < en; p += 64){
      float2 ev = eaperm[p];
      float lg = lrelu(a_s[srcs[p]] + adv + ev.x*w0 + ev.y*w1);
      mx = fmaxf(mx, lg);
    }
    for (int off=32; off; off>>=1) mx = fmaxf(mx, __shfl_xor(mx, off));
    float sm = 0.f;
    for (int p = st + lane; p < en; p += 64){
      float2 ev = eaperm[p];
      float lg = lrelu(a_s[srcs[p]] + adv + ev.x*w0 + ev.y*w1);
      sm += expf(lg - mx);
    }
    for (int off=32; off; off>>=1) sm += __shfl_xor(sm, off);
    float inv = 1.f/sm;
    for (int p = st; p < en; ++p){
      float2 ev = eaperm[p];
      int s = srcs[p];
      float lg = lrelu(a_s[s] + adv + ev.x*w0 + ev.y*w1);
      float wgt = expf(lg - mx) * inv;
      ushort4 hv = h4[(size_t)s*64 + lane];
      ax += wgt*b2f(hv.x); ay += wgt*b2f(hv.y); az += wgt*b2f(hv.z); aw += wgt*b2f(hv.w);
    }
  }
  float4 bv = ((const float4*)bias)[lane];
  float4 o;
  o.x = fmaxf(ax + bv.x, 0.f);
  o.y = fmaxf(ay + bv.y, 0.f);
  o.z = fmaxf(az + bv.z, 0.f);
  o.w = fmaxf(aw + bv.w, 0.f);
  if (hasRes){
    ushort4 r = ((const ushort4*)xprev)[(size_t)w*64 + lane];
    o.x += b2f(r.x); o.y += b2f(r.y); o.z += b2f(r.z); o.w += b2f(r.w);
  }
  ushort4 ob; ob.x=f2b(o.x); ob.y=f2b(o.y); ob.z=f2b(o.z); ob.w=f2b(o.w);
  ((ushort4*)xnext)[(size_t)w*64 + lane] = ob;
  if (doNext){
    float4 a = ((const float4*)vsn)[lane];
    float4 b = ((const float4*)vdn)[lane];
    float s1 = o.x*a.x + o.y*a.y + o.z*a.z + o.w*a.w;
    float s2 = o.x*b.x + o.y*b.y + o.z*b.z + o.w*b.w;
    for (int off=32; off; off>>=1){ s1 += __shfl_xor(s1, off); s2 += __shfl_xor(s2, off); }
    if (lane==0){ asn[w] = s1; adn[w] = s2; }
  }
}

__device__ __forceinline__ int lowerb(const int* a, int n, int v){
  int lo=0, hi=n;
  while (lo < hi){ int m = (lo+hi)>>1; if (a[m] < v) lo = m+1; else hi = m; }
  return lo;
}

// bf16 x pooling: block per batch, coalesced column sums
__global__ void pool_k(const unsigned short* __restrict__ x, const int* __restrict__ batch,
                       float* __restrict__ out){
  int b = blockIdx.x, t = threadIdx.x; // 256
  int st = lowerb(batch, NNODE, b), en = lowerb(batch, NNODE, b+1);
  float s = 0.f;
  for (int i=st;i<en;i++) s += b2f(x[(size_t)i*DIM + t]);
  out[(size_t)b*DIM + t] = s / fmaxf((float)(en - st), 1.f);
}

// fused edge-MLP pool: hbatch sorted + src-CSR => batch b's edges contiguous.
__global__ void epool_k(const int* __restrict__ rp_src, const int* __restrict__ hbatch,
                        const float2* __restrict__ eaperm, const float* __restrict__ Wem,
                        const float* __restrict__ bem, float* __restrict__ epool){
  __shared__ float ps[8][33];
  int b = blockIdx.x, t = threadIdx.x; // 256
  int j = t & 31, g = t >> 5;
  int nst = lowerb(hbatch, NNODE, b), nen = lowerb(hbatch, NNODE, b+1);
  int est = rp_src[nst], een = rp_src[nen];
  float w0 = Wem[j], w1 = Wem[32+j], bb = bem[j];
  float s = 0.f;
  for (int p = est + g; p < een; p += 8){
    float2 e = eaperm[p];
    s += fmaxf(e.x*w0 + e.y*w1 + bb, 0.f);
  }
  ps[g][j] = s; __syncthreads();
  if (g == 0){
    float tot = 0.f;
    #pragma unroll
    for (int gg=0; gg<8; gg++) tot += ps[gg][j];
    epool[(size_t)b*32 + j] = tot / fmaxf((float)(een - est), 1.f);
  }
}

__global__ void head_k(const float* __restrict__ hpool, const float* __restrict__ opool,
                       const float* __restrict__ epool,
                       const float* __restrict__ Wp1, const float* __restrict__ bp1,
                       const float* __restrict__ Wp2, const float* __restrict__ bp2,
                       float* __restrict__ out){
  __shared__ float emb[EMBD];
  __shared__ float red[256];
  int b = blockIdx.x, t = threadIdx.x; // 256
  emb[t] = hpool[(size_t)b*DIM + t];
  emb[DIM + t] = opool[(size_t)b*DIM + t];
  if (t < 32) emb[2*DIM + t] = epool[(size_t)b*32 + t];
  __syncthreads();
  for (int h = 0; h < 2; ++h){
    const float* Wp = h? Wp2 : Wp1;
    const float* bp = h? bp2 : bp1;
    float logit = -INFINITY;
    if (t < CC){
      float s = bp[t];
      for (int k=0;k<EMBD;k++) s += emb[k]*Wp[(size_t)k*CC + t];
      logit = s;
    }
    red[t] = logit; __syncthreads();
    for (int off=128; off; off>>=1){ if (t<off) red[t] = fmaxf(red[t], red[t+off]); __syncthreads(); }
    float mx = red[0]; __syncthreads();
    float ex = (t < CC) ? expf(logit - mx) : 0.f;
    red[t] = ex; __syncthreads();
    for (int off=128; off; off>>=1){ if (t<off) red[t] += red[t+off]; __syncthreads(); }
    float sm = red[0]; __syncthreads();
    if (t < CC) out[((size_t)b*2 + h)*CC + t] = ex / sm;
  }
}

extern "C" void kernel_launch(void* const* d_in, const int* in_sizes, int n_in,
                              void* d_out, int out_size, void* d_ws, size_t ws_size,
                              hipStream_t stream) {
  (void)in_sizes; (void)n_in; (void)out_size; (void)ws_size;
  const float* xh_in   = (const float*)d_in[0];
  const float* xo_in   = (const float*)d_in[1];
  const int*   ei_ho   = (const int*)d_in[2];
  const int*   ei_oh   = (const int*)d_in[3];
  const float* ea_ho   = (const float*)d_in[4];
  const float* ea_oh   = (const float*)d_in[5];
  const int*   hbatch  = (const int*)d_in[6];
  const int*   obatch  = (const int*)d_in[7];
  const float* Wsrc_ho = (const float*)d_in[8];
  const float* Wdst_ho = (const float*)d_in[9];
  const float* asrc_ho = (const float*)d_in[10];
  const float* adst_ho = (const float*)d_in[11];
  const float* Wedge_ho= (const float*)d_in[12];
  const float* aedge_ho= (const float*)d_in[13];
  const float* bias_ho = (const float*)d_in[14];
  const float* Wsrc_oh = (const float*)d_in[15];
  const float* Wdst_oh = (const float*)d_in[16];
  const float* asrc_oh = (const float*)d_in[17];
  const float* adst_oh = (const float*)d_in[18];
  const float* Wedge_oh= (const float*)d_in[19];
  const float* aedge_oh= (const float*)d_in[20];
  const float* bias_oh = (const float*)d_in[21];
  const float* W_emlp  = (const float*)d_in[22];
  const float* b_emlp  = (const float*)d_in[23];
  const float* W_p1    = (const float*)d_in[24];
  const float* b_p1    = (const float*)d_in[25];
  const float* W_p2    = (const float*)d_in[26];
  const float* b_p2    = (const float*)d_in[27];
  float* out = (float*)d_out;

  size_t ND = (size_t)NNODE*DIM;
  float* f = (float*)d_ws;
  float* aset0 = f;                        // [asho adho asoh adoh] set 0
  float* aset1 = aset0 + 4*NNODE;          // set 1
  float* vbuf  = aset1 + 4*NNODE;          // 32*256
  float* webuf = vbuf + 32*DIM;            // 32
  float* hpool = webuf + 32;               // BB*DIM
  float* opool = hpool + (size_t)BB*DIM;
  float* epool = opool + (size_t)BB*DIM;   // BB*32
  float2* eap_ho  = (float2*)(epool + (size_t)BB*32);   // E float2
  float2* eap_oh  = eap_ho + EDG;
  float2* eap_src = eap_oh + EDG;
  unsigned short* xhb_in = (unsigned short*)(eap_src + EDG);  // 6 x ND bf16
  unsigned short* xob_in = xhb_in + ND;
  unsigned short* xhb0 = xob_in + ND;
  unsigned short* xhb1 = xhb0 + ND;
  unsigned short* xob0 = xhb1 + ND;
  unsigned short* xob1 = xob0 + ND;
  unsigned short* hSb  = xob1 + ND;        // ND bf16
  unsigned short* Wtb  = hSb + ND;         // 2*8*65536 bf16
  int* cnt_ho  = (int*)(Wtb + (size_t)2*LAY*DIM*DIM);
  int* cnt_oh  = cnt_ho + NNODE;
  int* cnt_src = cnt_oh + NNODE;
  int* rp_ho   = cnt_src + NNODE;
  int* rp_oh   = rp_ho + NNODE + 1;
  int* rp_src  = rp_oh + NNODE + 1;
  int* srcs_ho = rp_src + NNODE + 1;
  int* srcs_oh = srcs_ho + EDG;
  int* bsum    = srcs_oh + EDG;            // 3*SCB
  int* boff    = bsum + 3*SCB;             // 3*SCB

  hipMemsetAsync(cnt_ho, 0, sizeof(int)*3*NNODE, stream);
  vcompute_k<<<2048, 256, 0, stream>>>(Wsrc_ho, Wdst_ho, asrc_ho, adst_ho,
                                       Wsrc_oh, Wdst_oh, asrc_oh, adst_oh, vbuf);
  wecompute_k<<<16, 64, 0, stream>>>(Wedge_ho, aedge_ho, Wedge_oh, aedge_oh, webuf);
  wtconv_k<<<4096, 256, 0, stream>>>(Wsrc_ho, Wsrc_oh, Wtb);
  xconv_k<<<12500, 256, 0, stream>>>(xh_in, xhb_in, (int)(ND/4));
  xconv_k<<<12500, 256, 0, stream>>>(xo_in, xob_in, (int)(ND/4));
  hist3_k<<<dim3(1954,3), 256, 0, stream>>>(ei_ho, ei_oh, cnt_ho, cnt_oh, cnt_src);
  scanA_k<<<dim3(SCB,3), 256, 0, stream>>>(cnt_ho, cnt_oh, cnt_src, bsum);
  scanB_k<<<1, 64, 0, stream>>>(bsum, boff, rp_ho, rp_oh, rp_src);
  scanC_k<<<dim3(SCB,3), 256, 0, stream>>>(cnt_ho, cnt_oh, cnt_src, boff, rp_ho, rp_oh, rp_src);
  hipMemsetAsync(cnt_ho, 0, sizeof(int)*3*NNODE, stream);            // reuse as cursors
  scatter_k<<<1954, 256, 0, stream>>>(ei_ho, ea_ho, rp_ho, cnt_ho, srcs_ho, eap_ho);
  scatter_k<<<1954, 256, 0, stream>>>(ei_oh, ea_oh, rp_oh, cnt_oh, srcs_oh, eap_oh);
  scatter_src_k<<<1954, 256, 0, stream>>>(ei_ho, ea_ho, rp_src, cnt_src, eap_src);

  // layer-0 a_s/a_d from fp32 inputs
  dgemv_k<<<12500, 256, 0, stream>>>(xh_in, vbuf + (size_t)0*DIM, vbuf + (size_t)3*DIM,
                                     aset0 + 0*NNODE, aset0 + 3*NNODE);
  dgemv_k<<<12500, 256, 0, stream>>>(xo_in, vbuf + (size_t)2*DIM, vbuf + (size_t)1*DIM,
                                     aset0 + 2*NNODE, aset0 + 1*NNODE);

  const unsigned short* xh = xhb_in;
  const unsigned short* xo = xob_in;
  unsigned short* xh_bufs[2] = {xhb0, xhb1};
  unsigned short* xo_bufs[2] = {xob0, xob1};
  float* asets[2] = {aset0, aset1};
  for (int l = 0; l < LAY; ++l){
    unsigned short* xo_n = xo_bufs[l & 1];
    unsigned short* xh_n = xh_bufs[l & 1];
    float* cur = asets[l & 1];
    float* nxt = asets[(l & 1) ^ 1];
    int doNext = (l < LAY-1);
    int ln = doNext ? (l+1) : l;   // valid vbuf index even when unused
    // relation ho: src=human, dst=object -> new xo; epilogue: asoh,adho for l+1
    gemmb_k<<<dim3(2, 391), 256, 0, stream>>>(xh, Wtb + (size_t)l*DIM*DIM, hSb, NNODE);
    attn_k<<<12500, 256, 0, stream>>>(rp_ho, srcs_ho, eap_ho,
                                      cur + 0*NNODE, cur + 1*NNODE,
                                      webuf + (size_t)(l*2+0)*2, hSb,
                                      bias_ho + (size_t)l*DIM, xo, xo_n,
                                      vbuf + (size_t)(ln*4+2)*DIM, vbuf + (size_t)(ln*4+1)*DIM,
                                      nxt + 2*NNODE, nxt + 1*NNODE, l > 0, doNext);
    // relation oh: src=object, dst=human -> new xh; epilogue: asho,adoh for l+1
    gemmb_k<<<dim3(2, 391), 256, 0, stream>>>(xo, Wtb + (size_t)(LAY + l)*DIM*DIM, hSb, NNODE);
    attn_k<<<12500, 256, 0, stream>>>(rp_oh, srcs_oh, eap_oh,
                                      cur + 2*NNODE, cur + 3*NNODE,
                                      webuf + (size_t)(l*2+1)*2, hSb,
                                      bias_oh + (size_t)l*DIM, xh, xh_n,
                                      vbuf + (size_t)(ln*4+0)*DIM, vbuf + (size_t)(ln*4+3)*DIM,
                                      nxt + 0*NNODE, nxt + 3*NNODE, l > 0, doNext);
    xh = xh_n; xo = xo_n;
  }

  pool_k<<<BB, 256, 0, stream>>>(xh, hbatch, hpool);
  pool_k<<<BB, 256, 0, stream>>>(xo, obatch, opool);
  epool_k<<<BB, 256, 0, stream>>>(rp_src, hbatch, eap_src, W_emlp, b_emlp, epool);
  head_k<<<BB, 256, 0, stream>>>(hpool, opool, epool, W_p1, b_p1, W_p2, b_p2, out);
}

// Round 7
// 1559.904 us; speedup vs baseline: 3.2958x; 1.1166x over previous
//
#include <hip/hip_runtime.h>
#include <math.h>

// HELPv3: 8-layer bipartite GAT + pooling + 2 softmax heads.
// R7: (1) privatized histogram (LDS windows + private copies, NO global atomics;
//         scans sum the 16 copies) - was 64us/46MB-write hist3_k
//     (2) dispatch fusion: gemm z=2, attn y=2, xconv+dgemv fused, scatter y=3, pool y=2
//     (3) attn gather unrolled 8-way
// Carried: bf16 MFMA GEMM, bf16 x-stream, CSR epool, fused epilogue GEMVs.

#define NNODE 50000
#define EDG   500000
#define DIM   256
#define LAY   8
#define BB    512
#define CC    117
#define EMBD  544
#define SCB   49          // scan blocks: 49*1024 >= 50000
#define HW    16384       // hist window (nodes), 64KB LDS
#define HC    16          // hist chunk count (private copies)
#define HNW   4           // windows: 4*16384 >= 50000

typedef short bf16x8 __attribute__((ext_vector_type(8)));
typedef float f32x4  __attribute__((ext_vector_type(4)));

static __device__ __forceinline__ float lrelu(float x){ return x >= 0.f ? x : 0.2f*x; }
static __device__ __forceinline__ unsigned short f2b(float f){
  unsigned int u = __float_as_uint(f);
  unsigned int r = (u + 0x7fffu + ((u >> 16) & 1u)) >> 16;   // RNE
  return (unsigned short)r;
}
static __device__ __forceinline__ float b2f(unsigned short u){
  return __uint_as_float(((unsigned int)u) << 16);
}

// v[k] = sum_j W[k*256+j]*a[j] for 32 (l,rel,which) combos; one wave per output k
__global__ void vcompute_k(const float* __restrict__ Wsho, const float* __restrict__ Wdho,
                           const float* __restrict__ asho, const float* __restrict__ adho,
                           const float* __restrict__ Wsoh, const float* __restrict__ Wdoh,
                           const float* __restrict__ asoh, const float* __restrict__ adoh,
                           float* __restrict__ vbuf){
  int gid = blockIdx.x*blockDim.x + threadIdx.x;
  int wv = gid >> 6, lane = gid & 63;
  if (wv >= 32*DIM) return;
  int p = wv >> 8, k = wv & 255;
  int which = p & 1, rel = (p>>1)&1, l = p>>2;
  const float* W; const float* a;
  if (rel==0){ W = which? Wdho : Wsho; a = which? adho : asho; }
  else       { W = which? Wdoh : Wsoh; a = which? adoh : asoh; }
  W += (size_t)l*DIM*DIM; a += (size_t)l*DIM;
  const float4* w4 = (const float4*)(W + (size_t)k*DIM);
  const float4* a4 = (const float4*)a;
  float4 wv4 = w4[lane], av4 = a4[lane];
  float s = wv4.x*av4.x + wv4.y*av4.y + wv4.z*av4.z + wv4.w*av4.w;
  for (int off=32; off; off>>=1) s += __shfl_xor(s, off);
  if (lane==0) vbuf[(size_t)p*DIM + k] = s;
}

__global__ void wecompute_k(const float* __restrict__ Weho, const float* __restrict__ aeho,
                            const float* __restrict__ Weoh, const float* __restrict__ aeoh,
                            float* __restrict__ webuf){
  int blk = blockIdx.x;            // l*2 + rel
  int rel = blk & 1, l = blk >> 1;
  const float* We = rel? Weoh : Weho;
  const float* ae = rel? aeoh : aeho;
  int lane = threadIdx.x;          // 64
  const float4* w0 = (const float4*)(We + (size_t)l*2*DIM);
  const float4* w1 = (const float4*)(We + (size_t)l*2*DIM + DIM);
  const float4* a4 = (const float4*)(ae + (size_t)l*DIM);
  float4 av = a4[lane], x0 = w0[lane], x1 = w1[lane];
  float s0 = x0.x*av.x + x0.y*av.y + x0.z*av.z + x0.w*av.w;
  float s1 = x1.x*av.x + x1.y*av.y + x1.z*av.z + x1.w*av.w;
  for (int off=32; off; off>>=1){ s0 += __shfl_xor(s0, off); s1 += __shfl_xor(s1, off); }
  if (lane==0){ webuf[blk*2] = s0; webuf[blk*2+1] = s1; }
}

// privatized histogram: block (x=chunk, y=window, z=array) counts its chunk's
// in-window keys in LDS, writes private copy (coalesced, no atomics).
// phist[((z*HNW + y)*HC + x)*HW + off]
__global__ void histp_k(const int* __restrict__ ei_ho, const int* __restrict__ ei_oh,
                        int* __restrict__ phist){
  __shared__ int h[HW];
  int x = blockIdx.x, y = blockIdx.y, z = blockIdx.z, t = threadIdx.x;
  for (int i=t; i<HW; i+=256) h[i] = 0;
  __syncthreads();
  const int* keys = (z==0)? (ei_ho + EDG) : (z==1)? (ei_oh + EDG) : ei_ho;
  int lo = y << 14;
  int e0 = x * (EDG/HC), e1 = e0 + (EDG/HC);
  for (int e = e0 + t; e < e1; e += 256){
    int k = keys[e] - lo;
    if ((unsigned)k < (unsigned)HW) atomicAdd(&h[k], 1);
  }
  __syncthreads();
  int* dst = phist + (size_t)(((z*HNW + y)*HC + x))*HW;
  for (int i=t; i<HW; i+=256) dst[i] = h[i];
}

static __device__ __forceinline__ int4 phist_sum4(const int* __restrict__ phist,
                                                  int z, int idx){
  int win = idx >> 14, off = idx & (HW-1);
  const int* base = phist + (size_t)((z*HNW + win)*HC)*HW + off;
  int4 s = make_int4(0,0,0,0);
  #pragma unroll
  for (int c=0;c<HC;c++){
    int4 v = *(const int4*)(base + (size_t)c*HW);
    s.x += v.x; s.y += v.y; s.z += v.z; s.w += v.w;
  }
  return s;
}

// Phase A: per-block sums (grid SCB x 3, 256 thr, 4 elem/thr)
__global__ void scanA_k(const int* __restrict__ phist, int* __restrict__ bsum){
  __shared__ int sh[256];
  int y = blockIdx.y, b = blockIdx.x, t = threadIdx.x;
  int idx = b*1024 + t*4;
  int s = 0;
  if (idx + 3 < NNODE){
    int4 v = phist_sum4(phist, y, idx);
    s = v.x + v.y + v.z + v.w;
  } else {
    for (int j=0;j<4;j++) if (idx+j < NNODE){
      int win = (idx+j) >> 14, off = (idx+j) & (HW-1);
      for (int c=0;c<HC;c++) s += phist[(size_t)((y*HNW+win)*HC+c)*HW + off];
    }
  }
  sh[t] = s; __syncthreads();
  for (int off=128; off; off>>=1){ if (t<off) sh[t] += sh[t+off]; __syncthreads(); }
  if (t==0) bsum[y*SCB + b] = sh[0];
}

__global__ void scanB_k(int* __restrict__ bsum, int* __restrict__ boff,
                        int* __restrict__ rp0, int* __restrict__ rp1, int* __restrict__ rp2){
  int t = threadIdx.x;
  if (t >= 3) return;
  int run = 0;
  for (int i=0;i<SCB;i++){ boff[t*SCB+i] = run; run += bsum[t*SCB+i]; }
  int* rp = (t==0)? rp0 : (t==1)? rp1 : rp2;
  rp[NNODE] = run;
}

__global__ void scanC_k(const int* __restrict__ phist, const int* __restrict__ boff,
                        int* __restrict__ rp0, int* __restrict__ rp1, int* __restrict__ rp2){
  __shared__ int sh[256];
  int y = blockIdx.y, b = blockIdx.x, t = threadIdx.x;
  int* rp = (y==0)? rp0 : (y==1)? rp1 : rp2;
  int idx = b*1024 + t*4;
  int c[4] = {0,0,0,0};
  if (idx + 3 < NNODE){
    int4 v = phist_sum4(phist, y, idx);
    c[0]=v.x; c[1]=v.y; c[2]=v.z; c[3]=v.w;
  } else {
    for (int j=0;j<4;j++) if (idx+j < NNODE){
      int win = (idx+j) >> 14, off = (idx+j) & (HW-1);
      for (int cc=0;cc<HC;cc++) c[j] += phist[(size_t)((y*HNW+win)*HC+cc)*HW + off];
    }
  }
  int mysum = c[0]+c[1]+c[2]+c[3];
  sh[t] = mysum; __syncthreads();
  for (int off=1; off<256; off<<=1){
    int v = (t>=off) ? sh[t-off] : 0;
    __syncthreads();
    sh[t] += v;
    __syncthreads();
  }
  int base = boff[y*SCB + b] + (sh[t] - mysum);
  int run = 0;
  for (int j=0;j<4;j++){
    if (idx+j < NNODE) rp[idx+j] = base + run;
    run += c[j];
  }
}

// fused scatters: y=0 dst(ho), y=1 dst(oh), y=2 src(ho)
__global__ void scatter3_k(const int* __restrict__ ei_ho, const int* __restrict__ ei_oh,
                           const float* __restrict__ ea_ho, const float* __restrict__ ea_oh,
                           const int* __restrict__ rp0, const int* __restrict__ rp1,
                           const int* __restrict__ rp2, int* __restrict__ cur,
                           int* __restrict__ srcs0, int* __restrict__ srcs1,
                           float2* __restrict__ eap0, float2* __restrict__ eap1,
                           float2* __restrict__ eap2){
  int e = blockIdx.x*blockDim.x + threadIdx.x;
  if (e >= EDG) return;
  int y = blockIdx.y;
  if (y == 0){
    int d = ei_ho[EDG + e];
    int pos = rp0[d] + atomicAdd(&cur[d], 1);
    srcs0[pos] = ei_ho[e];
    eap0[pos] = make_float2(ea_ho[2*e], ea_ho[2*e+1]);
  } else if (y == 1){
    int d = ei_oh[EDG + e];
    int pos = rp1[d] + atomicAdd(&cur[NNODE + d], 1);
    srcs1[pos] = ei_oh[e];
    eap1[pos] = make_float2(ea_oh[2*e], ea_oh[2*e+1]);
  } else {
    int s = ei_ho[e];
    int pos = rp2[s] + atomicAdd(&cur[2*NNODE + s], 1);
    eap2[pos] = make_float2(ea_ho[2*e], ea_ho[2*e+1]);
  }
}

// fused fp32->bf16 convert + layer-0 a_s/a_d dots. One wave per row; z = h/o.
__global__ void xcdg_k(const float* __restrict__ xh_in, const float* __restrict__ xo_in,
                       unsigned short* __restrict__ xhb, unsigned short* __restrict__ xob,
                       const float* __restrict__ vbuf, float* __restrict__ aset){
  int gid = blockIdx.x*blockDim.x + threadIdx.x;
  int w = gid >> 6, lane = gid & 63;
  if (w >= NNODE) return;
  int z = blockIdx.y;
  const float* X = z? xo_in : xh_in;
  unsigned short* O = z? xob : xhb;
  const float* v1 = vbuf + (size_t)(z? 2:0)*DIM;   // as (src-role)
  const float* v2 = vbuf + (size_t)(z? 1:3)*DIM;   // ad (dst-role)
  float* o1 = aset + (size_t)(z? 2:0)*NNODE;
  float* o2 = aset + (size_t)(z? 1:3)*NNODE;
  float4 xv = ((const float4*)(X + (size_t)w*DIM))[lane];
  ushort4 ob; ob.x=f2b(xv.x); ob.y=f2b(xv.y); ob.z=f2b(xv.z); ob.w=f2b(xv.w);
  ((ushort4*)O)[(size_t)w*64 + lane] = ob;
  float4 a = ((const float4*)v1)[lane];
  float4 b = ((const float4*)v2)[lane];
  float s1 = xv.x*a.x + xv.y*a.y + xv.z*a.z + xv.w*a.w;
  float s2 = xv.x*b.x + xv.y*b.y + xv.z*b.z + xv.w*b.w;
  for (int off=32; off; off>>=1){ s1 += __shfl_xor(s1, off); s2 += __shfl_xor(s2, off); }
  if (lane==0){ o1[w] = s1; o2[w] = s2; }
}

// Wt[rel][l][n][k] = bf16(W[rel][l][k][n])
__global__ void wtconv_k(const float* __restrict__ Who, const float* __restrict__ Woh,
                         unsigned short* __restrict__ Wt){
  int gid = blockIdx.x*blockDim.x + threadIdx.x;   // < 1048576
  int rel = gid >> 19;
  int rem = gid & ((1<<19)-1);
  int l = rem >> 16;
  int idx = rem & 65535;
  int n = idx >> 8, k = idx & 255;
  const float* W = rel ? Woh : Who;
  Wt[gid] = f2b(W[(size_t)l*65536 + (size_t)k*256 + n]);
}

// fused GEMM pair: z=0: H0=xh@Wl_ho; z=1: H1=xo@Wl_oh. 128x128 tile, 4 waves.
__global__ __launch_bounds__(256) void gemmb2_k(const unsigned short* __restrict__ A0,
                                                const unsigned short* __restrict__ A1,
                                                const unsigned short* __restrict__ B0,
                                                const unsigned short* __restrict__ B1,
                                                unsigned short* __restrict__ H0,
                                                unsigned short* __restrict__ H1, int M){
  __shared__ __align__(16) unsigned short As[4096];
  __shared__ __align__(16) unsigned short Bs[4096];
  int z = blockIdx.z;
  const unsigned short* A  = z? A1 : A0;
  const unsigned short* Bt = z? B1 : B0;
  unsigned short* H        = z? H1 : H0;
  int tid = threadIdx.x;
  int col0 = blockIdx.x * 128;
  int row0 = blockIdx.y * 128;
  int w = tid >> 6, lane = tid & 63;
  int q = lane >> 4, ml = lane & 15;
  f32x4 acc[2][8];
  #pragma unroll
  for (int i=0;i<2;i++)
    #pragma unroll
    for (int j=0;j<8;j++) acc[i][j] = (f32x4){0.f,0.f,0.f,0.f};
  int srow = tid >> 2;    // 0..63
  int sq   = tid & 3;
  for (int k0 = 0; k0 < 256; k0 += 32){
    #pragma unroll
    for (int p = 0; p < 2; ++p){
      int row = p*64 + srow;
      int gr = row0 + row;
      uint4 av = make_uint4(0,0,0,0);
      if (gr < M) av = *(const uint4*)(A + (size_t)gr*256 + k0 + sq*8);
      *(uint4*)&As[((((row>>4)*4) + sq)*16 + (row&15))*8] = av;
      int gc = col0 + row;
      uint4 bv = *(const uint4*)(Bt + (size_t)gc*256 + k0 + sq*8);
      *(uint4*)&Bs[((((row>>4)*4) + sq)*16 + (row&15))*8] = bv;
    }
    __syncthreads();
    bf16x8 a0 = *(const bf16x8*)&As[(((2*w+0)*4 + q)*16 + ml)*8];
    bf16x8 a1 = *(const bf16x8*)&As[(((2*w+1)*4 + q)*16 + ml)*8];
    #pragma unroll
    for (int nf = 0; nf < 8; ++nf){
      bf16x8 b = *(const bf16x8*)&Bs[((nf*4 + q)*16 + ml)*8];
      acc[0][nf] = __builtin_amdgcn_mfma_f32_16x16x32_bf16(a0, b, acc[0][nf], 0,0,0);
      acc[1][nf] = __builtin_amdgcn_mfma_f32_16x16x32_bf16(a1, b, acc[1][nf], 0,0,0);
    }
    __syncthreads();
  }
  #pragma unroll
  for (int mf = 0; mf < 2; ++mf){
    #pragma unroll
    for (int r = 0; r < 4; ++r){
      int gr = row0 + 32*w + 16*mf + q*4 + r;
      if (gr < M){
        #pragma unroll
        for (int nf = 0; nf < 8; ++nf)
          H[(size_t)gr*256 + col0 + nf*16 + ml] = f2b(acc[mf][nf][r]);
      }
    }
  }
}

// fused attn pair (y = relation). One wave per dst node.
__global__ void attn2_k(const int* __restrict__ rp0, const int* __restrict__ srcs0,
                        const float2* __restrict__ eap0,
                        const int* __restrict__ rp1, const int* __restrict__ srcs1,
                        const float2* __restrict__ eap1,
                        const float* __restrict__ cur_a, float* __restrict__ nxt_a,
                        const float* __restrict__ wepl,
                        const unsigned short* __restrict__ hs0,
                        const unsigned short* __restrict__ hs1,
                        const float* __restrict__ bias0, const float* __restrict__ bias1,
                        const unsigned short* __restrict__ xprev0,
                        const unsigned short* __restrict__ xprev1,
                        unsigned short* __restrict__ xnext0,
                        unsigned short* __restrict__ xnext1,
                        const float* __restrict__ vbl,
                        int hasRes, int doNext){
  int gid = blockIdx.x*blockDim.x + threadIdx.x;
  int w = gid >> 6, lane = gid & 63;
  if (w >= NNODE) return;
  int rel = blockIdx.y;
  const int* rowptr = rel? rp1 : rp0;
  const int* srcs   = rel? srcs1 : srcs0;
  const float2* eaperm = rel? eap1 : eap0;
  const float* a_s = cur_a + (size_t)(rel? 2:0)*NNODE;
  const float* a_d = cur_a + (size_t)(rel? 3:1)*NNODE;
  float w0 = wepl[rel? 2:0], w1 = wepl[rel? 3:1];
  const unsigned short* hs = rel? hs1 : hs0;
  const float* bias = rel? bias1 : bias0;
  const unsigned short* xprev = rel? xprev1 : xprev0;
  unsigned short* xnext = rel? xnext1 : xnext0;

  int st = rowptr[w], en = rowptr[w+1];
  int deg = en - st;
  float adv = a_d[w];
  float ax=0.f, ay=0.f, az=0.f, aw=0.f;
  const ushort4* h4 = (const ushort4*)hs;
  if (deg > 0 && deg <= 64){
    int sreg = 0; float lg = -INFINITY;
    if (lane < deg){
      sreg = srcs[st + lane];
      float2 ev = eaperm[st + lane];
      lg = lrelu(a_s[sreg] + adv + ev.x*w0 + ev.y*w1);
    }
    float mx = lg;
    for (int off=32; off; off>>=1) mx = fmaxf(mx, __shfl_xor(mx, off));
    float ex = (lane < deg) ? expf(lg - mx) : 0.f;
    float sm = ex;
    for (int off=32; off; off>>=1) sm += __shfl_xor(sm, off);
    float wgt = ex / sm;
    int i = 0;
    for (; i + 7 < deg; i += 8){
      float wi[8]; int si[8];
      #pragma unroll
      for (int j=0;j<8;j++){ wi[j] = __shfl(wgt, i+j); si[j] = __shfl(sreg, i+j); }
      ushort4 hv[8];
      #pragma unroll
      for (int j=0;j<8;j++) hv[j] = h4[(size_t)si[j]*64 + lane];
      #pragma unroll
      for (int j=0;j<8;j++){
        ax += wi[j]*b2f(hv[j].x); ay += wi[j]*b2f(hv[j].y);
        az += wi[j]*b2f(hv[j].z); aw += wi[j]*b2f(hv[j].w);
      }
    }
    for (; i + 3 < deg; i += 4){
      float wi[4]; int si[4];
      #pragma unroll
      for (int j=0;j<4;j++){ wi[j] = __shfl(wgt, i+j); si[j] = __shfl(sreg, i+j); }
      ushort4 hv[4];
      #pragma unroll
      for (int j=0;j<4;j++) hv[j] = h4[(size_t)si[j]*64 + lane];
      #pragma unroll
      for (int j=0;j<4;j++){
        ax += wi[j]*b2f(hv[j].x); ay += wi[j]*b2f(hv[j].y);
        az += wi[j]*b2f(hv[j].z); aw += wi[j]*b2f(hv[j].w);
      }
    }
    for (; i < deg; ++i){
      float wi = __shfl(wgt, i);
      int   si = __shfl(sreg, i);
      ushort4 hv = h4[(size_t)si*64 + lane];
      ax += wi*b2f(hv.x); ay += wi*b2f(hv.y); az += wi*b2f(hv.z); aw += wi*b2f(hv.w);
    }
  } else if (deg > 64){
    float mx = -INFINITY;
    for (int p = st + lane; p < en; p += 64){
      float2 ev = eaperm[p];
      float lg = lrelu(a_s[srcs[p]] + adv + ev.x*w0 + ev.y*w1);
      mx = fmaxf(mx, lg);
    }
    for (int off=32; off; off>>=1) mx = fmaxf(mx, __shfl_xor(mx, off));
    float sm = 0.f;
    for (int p = st + lane; p < en; p += 64){
      float2 ev = eaperm[p];
      float lg = lrelu(a_s[srcs[p]] + adv + ev.x*w0 + ev.y*w1);
      sm += expf(lg - mx);
    }
    for (int off=32; off; off>>=1) sm += __shfl_xor(sm, off);
    float inv = 1.f/sm;
    for (int p = st; p < en; ++p){
      float2 ev = eaperm[p];
      int s = srcs[p];
      float lg = lrelu(a_s[s] + adv + ev.x*w0 + ev.y*w1);
      float wgt = expf(lg - mx) * inv;
      ushort4 hv = h4[(size_t)s*64 + lane];
      ax += wgt*b2f(hv.x); ay += wgt*b2f(hv.y); az += wgt*b2f(hv.z); aw += wgt*b2f(hv.w);
    }
  }
  float4 bv = ((const float4*)bias)[lane];
  float4 o;
  o.x = fmaxf(ax + bv.x, 0.f);
  o.y = fmaxf(ay + bv.y, 0.f);
  o.z = fmaxf(az + bv.z, 0.f);
  o.w = fmaxf(aw + bv.w, 0.f);
  if (hasRes){
    ushort4 r = ((const ushort4*)xprev)[(size_t)w*64 + lane];
    o.x += b2f(r.x); o.y += b2f(r.y); o.z += b2f(r.z); o.w += b2f(r.w);
  }
  ushort4 ob; ob.x=f2b(o.x); ob.y=f2b(o.y); ob.z=f2b(o.z); ob.w=f2b(o.w);
  ((ushort4*)xnext)[(size_t)w*64 + lane] = ob;
  if (doNext){
    const float* vsn = vbl + (size_t)(rel? 0:2)*DIM;
    const float* vdn = vbl + (size_t)(rel? 3:1)*DIM;
    float* asn = nxt_a + (size_t)(rel? 0:2)*NNODE;
    float* adn = nxt_a + (size_t)(rel? 3:1)*NNODE;
    float4 a = ((const float4*)vsn)[lane];
    float4 b = ((const float4*)vdn)[lane];
    float s1 = o.x*a.x + o.y*a.y + o.z*a.z + o.w*a.w;
    float s2 = o.x*b.x + o.y*b.y + o.z*b.z + o.w*b.w;
    for (int off=32; off; off>>=1){ s1 += __shfl_xor(s1, off); s2 += __shfl_xor(s2, off); }
    if (lane==0){ asn[w] = s1; adn[w] = s2; }
  }
}

__device__ __forceinline__ int lowerb(const int* a, int n, int v){
  int lo=0, hi=n;
  while (lo < hi){ int m = (lo+hi)>>1; if (a[m] < v) lo = m+1; else hi = m; }
  return lo;
}

// bf16 x pooling pair (y = h/o): block per batch, coalesced column sums
__global__ void pool2_k(const unsigned short* __restrict__ xh, const unsigned short* __restrict__ xo,
                        const int* __restrict__ hbatch, const int* __restrict__ obatch,
                        float* __restrict__ hpool, float* __restrict__ opool){
  int z = blockIdx.y;
  const unsigned short* x = z? xo : xh;
  const int* batch = z? obatch : hbatch;
  float* out = z? opool : hpool;
  int b = blockIdx.x, t = threadIdx.x; // 256
  int st = lowerb(batch, NNODE, b), en = lowerb(batch, NNODE, b+1);
  float s = 0.f;
  for (int i=st;i<en;i++) s += b2f(x[(size_t)i*DIM + t]);
  out[(size_t)b*DIM + t] = s / fmaxf((float)(en - st), 1.f);
}

// fused edge-MLP pool: hbatch sorted + src-CSR => batch b's edges contiguous.
__global__ void epool_k(const int* __restrict__ rp_src, const int* __restrict__ hbatch,
                        const float2* __restrict__ eaperm, const float* __restrict__ Wem,
                        const float* __restrict__ bem, float* __restrict__ epool){
  __shared__ float ps[8][33];
  int b = blockIdx.x, t = threadIdx.x; // 256
  int j = t & 31, g = t >> 5;
  int nst = lowerb(hbatch, NNODE, b), nen = lowerb(hbatch, NNODE, b+1);
  int est = rp_src[nst], een = rp_src[nen];
  float w0 = Wem[j], w1 = Wem[32+j], bb = bem[j];
  float s = 0.f;
  for (int p = est + g; p < een; p += 8){
    float2 e = eaperm[p];
    s += fmaxf(e.x*w0 + e.y*w1 + bb, 0.f);
  }
  ps[g][j] = s; __syncthreads();
  if (g == 0){
    float tot = 0.f;
    #pragma unroll
    for (int gg=0; gg<8; gg++) tot += ps[gg][j];
    epool[(size_t)b*32 + j] = tot / fmaxf((float)(een - est), 1.f);
  }
}

__global__ void head_k(const float* __restrict__ hpool, const float* __restrict__ opool,
                       const float* __restrict__ epool,
                       const float* __restrict__ Wp1, const float* __restrict__ bp1,
                       const float* __restrict__ Wp2, const float* __restrict__ bp2,
                       float* __restrict__ out){
  __shared__ float emb[EMBD];
  __shared__ float red[256];
  int b = blockIdx.x, t = threadIdx.x; // 256
  emb[t] = hpool[(size_t)b*DIM + t];
  emb[DIM + t] = opool[(size_t)b*DIM + t];
  if (t < 32) emb[2*DIM + t] = epool[(size_t)b*32 + t];
  __syncthreads();
  for (int h = 0; h < 2; ++h){
    const float* Wp = h? Wp2 : Wp1;
    const float* bp = h? bp2 : bp1;
    float logit = -INFINITY;
    if (t < CC){
      float s = bp[t];
      for (int k=0;k<EMBD;k++) s += emb[k]*Wp[(size_t)k*CC + t];
      logit = s;
    }
    red[t] = logit; __syncthreads();
    for (int off=128; off; off>>=1){ if (t<off) red[t] = fmaxf(red[t], red[t+off]); __syncthreads(); }
    float mx = red[0]; __syncthreads();
    float ex = (t < CC) ? expf(logit - mx) : 0.f;
    red[t] = ex; __syncthreads();
    for (int off=128; off; off>>=1){ if (t<off) red[t] += red[t+off]; __syncthreads(); }
    float sm = red[0]; __syncthreads();
    if (t < CC) out[((size_t)b*2 + h)*CC + t] = ex / sm;
  }
}

extern "C" void kernel_launch(void* const* d_in, const int* in_sizes, int n_in,
                              void* d_out, int out_size, void* d_ws, size_t ws_size,
                              hipStream_t stream) {
  (void)in_sizes; (void)n_in; (void)out_size; (void)ws_size;
  const float* xh_in   = (const float*)d_in[0];
  const float* xo_in   = (const float*)d_in[1];
  const int*   ei_ho   = (const int*)d_in[2];
  const int*   ei_oh   = (const int*)d_in[3];
  const float* ea_ho   = (const float*)d_in[4];
  const float* ea_oh   = (const float*)d_in[5];
  const int*   hbatch  = (const int*)d_in[6];
  const int*   obatch  = (const int*)d_in[7];
  const float* Wsrc_ho = (const float*)d_in[8];
  const float* Wdst_ho = (const float*)d_in[9];
  const float* asrc_ho = (const float*)d_in[10];
  const float* adst_ho = (const float*)d_in[11];
  const float* Wedge_ho= (const float*)d_in[12];
  const float* aedge_ho= (const float*)d_in[13];
  const float* bias_ho = (const float*)d_in[14];
  const float* Wsrc_oh = (const float*)d_in[15];
  const float* Wdst_oh = (const float*)d_in[16];
  const float* asrc_oh = (const float*)d_in[17];
  const float* adst_oh = (const float*)d_in[18];
  const float* Wedge_oh= (const float*)d_in[19];
  const float* aedge_oh= (const float*)d_in[20];
  const float* bias_oh = (const float*)d_in[21];
  const float* W_emlp  = (const float*)d_in[22];
  const float* b_emlp  = (const float*)d_in[23];
  const float* W_p1    = (const float*)d_in[24];
  const float* b_p1    = (const float*)d_in[25];
  const float* W_p2    = (const float*)d_in[26];
  const float* b_p2    = (const float*)d_in[27];
  float* out = (float*)d_out;

  size_t ND = (size_t)NNODE*DIM;
  float* f = (float*)d_ws;
  float* aset0 = f;                        // [asho adho asoh adoh] set 0
  float* aset1 = aset0 + 4*NNODE;          // set 1
  float* vbuf  = aset1 + 4*NNODE;          // 32*256
  float* webuf = vbuf + 32*DIM;            // 32
  float* hpool = webuf + 32;               // BB*DIM
  float* opool = hpool + (size_t)BB*DIM;
  float* epool = opool + (size_t)BB*DIM;   // BB*32
  float2* eap_ho  = (float2*)(epool + (size_t)BB*32);   // E float2
  float2* eap_oh  = eap_ho + EDG;
  float2* eap_src = eap_oh + EDG;
  unsigned short* xhb0 = (unsigned short*)(eap_src + EDG);  // 6 x ND bf16
  unsigned short* xhb1 = xhb0 + ND;        // also holds bf16(xh_in) initially
  unsigned short* xob0 = xhb1 + ND;
  unsigned short* xob1 = xob0 + ND;        // also holds bf16(xo_in) initially
  unsigned short* hSb0 = xob1 + ND;
  unsigned short* hSb1 = hSb0 + ND;
  unsigned short* Wtb  = hSb1 + ND;        // 2*8*65536 bf16
  int* cur     = (int*)(Wtb + (size_t)2*LAY*DIM*DIM);   // 3*NNODE cursors
  int* rp_ho   = cur + 3*NNODE;
  int* rp_oh   = rp_ho + NNODE + 1;
  int* rp_src  = rp_oh + NNODE + 1;
  int* srcs_ho = rp_src + NNODE + 1;
  int* srcs_oh = srcs_ho + EDG;
  int* bsum    = srcs_oh + EDG;            // 3*SCB
  int* boff    = bsum + 3*SCB;             // 3*SCB
  int* phist   = boff + 3*SCB;             // 3*HNW*HC*HW ints (~12.6MB)

  hipMemsetAsync(cur, 0, sizeof(int)*3*NNODE, stream);
  vcompute_k<<<2048, 256, 0, stream>>>(Wsrc_ho, Wdst_ho, asrc_ho, adst_ho,
                                       Wsrc_oh, Wdst_oh, asrc_oh, adst_oh, vbuf);
  wecompute_k<<<16, 64, 0, stream>>>(Wedge_ho, aedge_ho, Wedge_oh, aedge_oh, webuf);
  wtconv_k<<<4096, 256, 0, stream>>>(Wsrc_ho, Wsrc_oh, Wtb);
  histp_k<<<dim3(HC, HNW, 3), 256, 0, stream>>>(ei_ho, ei_oh, phist);
  scanA_k<<<dim3(SCB, 3), 256, 0, stream>>>(phist, bsum);
  scanB_k<<<1, 64, 0, stream>>>(bsum, boff, rp_ho, rp_oh, rp_src);
  scanC_k<<<dim3(SCB, 3), 256, 0, stream>>>(phist, boff, rp_ho, rp_oh, rp_src);
  scatter3_k<<<dim3(1954, 3), 256, 0, stream>>>(ei_ho, ei_oh, ea_ho, ea_oh,
                                                rp_ho, rp_oh, rp_src, cur,
                                                srcs_ho, srcs_oh, eap_ho, eap_oh, eap_src);
  // fp32->bf16 + layer-0 a_s/a_d
  xcdg_k<<<dim3(12500, 2), 256, 0, stream>>>(xh_in, xo_in, xhb1, xob1, vbuf, aset0);

  const unsigned short* xh = xhb1;
  const unsigned short* xo = xob1;
  unsigned short* xh_bufs[2] = {xhb0, xhb1};
  unsigned short* xo_bufs[2] = {xob0, xob1};
  float* asets[2] = {aset0, aset1};
  for (int l = 0; l < LAY; ++l){
    unsigned short* xo_n = xo_bufs[l & 1];
    unsigned short* xh_n = xh_bufs[l & 1];
    float* cur_a = asets[l & 1];
    float* nxt_a = asets[(l & 1) ^ 1];
    int doNext = (l < LAY-1);
    int ln = doNext ? (l+1) : l;   // valid vbuf index even when unused
    gemmb2_k<<<dim3(2, 391, 2), 256, 0, stream>>>(xh, xo,
                                                  Wtb + (size_t)l*DIM*DIM,
                                                  Wtb + (size_t)(LAY + l)*DIM*DIM,
                                                  hSb0, hSb1, NNODE);
    attn2_k<<<dim3(12500, 2), 256, 0, stream>>>(rp_ho, srcs_ho, eap_ho,
                                                rp_oh, srcs_oh, eap_oh,
                                                cur_a, nxt_a,
                                                webuf + (size_t)l*4,
                                                hSb0, hSb1,
                                                bias_ho + (size_t)l*DIM, bias_oh + (size_t)l*DIM,
                                                xo, xh, xo_n, xh_n,
                                                vbuf + (size_t)ln*4*DIM,
                                                l > 0, doNext);
    xh = xh_n; xo = xo_n;
  }

  pool2_k<<<dim3(BB, 2), 256, 0, stream>>>(xh, xo, hbatch, obatch, hpool, opool);
  epool_k<<<BB, 256, 0, stream>>>(rp_src, hbatch, eap_src, W_emlp, b_emlp, epool);
  head_k<<<BB, 256, 0, stream>>>(hpool, opool, epool, W_p1, b_p1, W_p2, b_p2, out);
}